// Round 18
// baseline (545.504 us; speedup 1.0000x reference)
//
#include <hip/hip_runtime.h>
#include <hip/hip_fp16.h>

#define NGRAPH 512
#define SCAN_T 256
#define SCAN_V 4
#define SCAN_B (SCAN_T * SCAN_V)

// bucket scheme: 1024 nodes per bucket, two-pass WG-private radix partition.
#define LB 10
#define NPB 1024
#define SHIFT 22
#define SMASK ((1 << SHIFT) - 1)
#define MAXB 512
#define GWG 512   // workgroups in partition passes

#define FSCALE 16777216.0f          // 2^24 fixed-point scale
#define FINV   (1.0f / 16777216.0f)

typedef int v4i __attribute__((ext_vector_type(4)));

__device__ __forceinline__ int ntl(const int* p) {
    return __builtin_nontemporal_load(p);
}
__device__ __forceinline__ v4i ntl4(const int* p) {
    return __builtin_nontemporal_load((const v4i*)p);
}

// ===================== two-pass partition =====================

// pass1: per-WG LDS bucket histogram over private chunk -> cnt[bucket][GWG]
__global__ void k_p1(const int* __restrict__ dst, int* __restrict__ cnt,
                     int E, int chunk, int nbuck) {
    __shared__ int hist[MAXB];
    int w = blockIdx.x;
    for (int i = threadIdx.x; i < nbuck; i += blockDim.x) hist[i] = 0;
    __syncthreads();
    int beg = w * chunk;
    int end = min(beg + chunk, E);
    if (beg < end) {
        if ((((uintptr_t)(dst + beg)) & 15) == 0) {
            const int4* d4 = (const int4*)(dst + beg);
            int n4 = (end - beg) >> 2;
            for (int i = threadIdx.x; i < n4; i += blockDim.x) {
                int4 d = d4[i];
                atomicAdd(&hist[d.x >> LB], 1);
                atomicAdd(&hist[d.y >> LB], 1);
                atomicAdd(&hist[d.z >> LB], 1);
                atomicAdd(&hist[d.w >> LB], 1);
            }
            for (int i = beg + (n4 << 2) + threadIdx.x; i < end; i += blockDim.x)
                atomicAdd(&hist[dst[i] >> LB], 1);
        } else {
            for (int i = beg + threadIdx.x; i < end; i += blockDim.x)
                atomicAdd(&hist[dst[i] >> LB], 1);
        }
    }
    __syncthreads();
    for (int b = threadIdx.x; b < nbuck; b += blockDim.x)
        cnt[(size_t)b * GWG + w] = hist[b];
}

// scanA: per-block (1024-elem) sums of cnt -> bs
__global__ void k_sA(const int* __restrict__ cnt, int* __restrict__ bs, int M) {
    __shared__ int sh[SCAN_T];
    int base = blockIdx.x * SCAN_B + threadIdx.x * SCAN_V;
    int s = 0;
#pragma unroll
    for (int k = 0; k < SCAN_V; ++k) {
        int idx = base + k;
        if (idx < M) s += cnt[idx];
    }
    sh[threadIdx.x] = s;
    __syncthreads();
    for (int o = SCAN_T / 2; o > 0; o >>= 1) {
        if (threadIdx.x < o) sh[threadIdx.x] += sh[threadIdx.x + o];
        __syncthreads();
    }
    if (threadIdx.x == 0) bs[blockIdx.x] = sh[0];
}

// scanB: single block, 1024 threads: exclusive scan of bs[0..nb)
__global__ void k_sB(int* __restrict__ bs, int nb) {
    __shared__ int sh[1024];
    int t = threadIdx.x;
    int v = (t < nb) ? bs[t] : 0;
    sh[t] = v;
    __syncthreads();
    for (int o = 1; o < 1024; o <<= 1) {
        int u = (t >= o) ? sh[t - o] : 0;
        __syncthreads();
        sh[t] += u;
        __syncthreads();
    }
    if (t < nb) bs[t] = sh[t] - v;
}

// scanC: full exclusive scan -> start[bucket][GWG]
__global__ void k_sC(const int* __restrict__ cnt, const int* __restrict__ bs,
                     int* __restrict__ start, int M) {
    __shared__ int sh[SCAN_T];
    int t = threadIdx.x;
    int base = blockIdx.x * SCAN_B + t * SCAN_V;
    int v[SCAN_V];
    int s = 0;
#pragma unroll
    for (int k = 0; k < SCAN_V; ++k) {
        int idx = base + k;
        v[k] = (idx < M) ? cnt[idx] : 0;
        s += v[k];
    }
    sh[t] = s;
    __syncthreads();
    for (int o = 1; o < SCAN_T; o <<= 1) {
        int u = (t >= o) ? sh[t - o] : 0;
        __syncthreads();
        sh[t] += u;
        __syncthreads();
    }
    int run = bs[blockIdx.x] + sh[t] - s;
#pragma unroll
    for (int k = 0; k < SCAN_V; ++k) {
        int idx = base + k;
        if (idx < M) {
            start[idx] = run;
            run += v[k];
        }
    }
}

// pass2: WG-private placement, zero global atomics. NT loads keep the
// streaming src/dst reads out of L2 so partial write lines survive long
// enough to coalesce; stores stay plain (nt stores break coalescing, R9).
__global__ void k_p2(const int* __restrict__ src, const int* __restrict__ dst,
                     const int* __restrict__ start, int* __restrict__ binned,
                     int E, int chunk, int nbuck) {
    __shared__ int cur[MAXB];
    int w = blockIdx.x;
    for (int b = threadIdx.x; b < nbuck; b += blockDim.x)
        cur[b] = start[(size_t)b * GWG + w];
    __syncthreads();
    int beg = w * chunk;
    int end = min(beg + chunk, E);
    if (beg >= end) return;
    if (((((uintptr_t)(dst + beg)) | ((uintptr_t)(src + beg))) & 15) == 0) {
        int n4 = (end - beg) >> 2;
        for (int i = threadIdx.x; i < n4; i += blockDim.x) {
            v4i s = ntl4(src + beg + (i << 2));
            v4i d = ntl4(dst + beg + (i << 2));
            binned[atomicAdd(&cur[d.x >> LB], 1)] = ((d.x & (NPB - 1)) << SHIFT) | s.x;
            binned[atomicAdd(&cur[d.y >> LB], 1)] = ((d.y & (NPB - 1)) << SHIFT) | s.y;
            binned[atomicAdd(&cur[d.z >> LB], 1)] = ((d.z & (NPB - 1)) << SHIFT) | s.z;
            binned[atomicAdd(&cur[d.w >> LB], 1)] = ((d.w & (NPB - 1)) << SHIFT) | s.w;
        }
        for (int i = beg + (n4 << 2) + threadIdx.x; i < end; i += blockDim.x) {
            int s = ntl(src + i), d = ntl(dst + i);
            binned[atomicAdd(&cur[d >> LB], 1)] = ((d & (NPB - 1)) << SHIFT) | s;
        }
    } else {
        for (int i = beg + threadIdx.x; i < end; i += blockDim.x) {
            int s = src[i], d = dst[i];
            binned[atomicAdd(&cur[d >> LB], 1)] = ((d & (NPB - 1)) << SHIFT) | s;
        }
    }
}

// ===================== per-bucket layers (LDS accumulators, 1024-thr blocks) ===

// degree hist -> dis, px
__global__ void k_boff(const int* __restrict__ start, const int* __restrict__ binned,
                       const float* __restrict__ x, float* __restrict__ dis,
                       float* __restrict__ px, int N, int E, int nbuck) {
    __shared__ int hist[NPB];
    int b = blockIdx.x;
    hist[threadIdx.x] = 0;
    __syncthreads();
    int a = start[(size_t)b * GWG];
    int e = (b + 1 < nbuck) ? start[(size_t)(b + 1) * GWG] : E;
    for (int j = a + threadIdx.x; j < e; j += NPB)
        atomicAdd(&hist[((unsigned)binned[j]) >> SHIFT], 1);
    __syncthreads();
    int node = (b << LB) + threadIdx.x;
    if (node < N) {
        float dv = rsqrtf((float)hist[threadIdx.x] + 1.0f);
        dis[node] = dv;
        px[node]  = x[node] * dv;
    }
}

// layer1: h1s(fp16x4) = relu(dis*(acc+px)*W1+b1)*dis
__global__ void k_g1(const int* __restrict__ start, const int* __restrict__ binned,
                     const float* __restrict__ px, const float* __restrict__ dis,
                     const float* __restrict__ W1, const float* __restrict__ b1,
                     uint2* __restrict__ h1s, int N, int E, int nbuck) {
    __shared__ float acc[NPB];
    int b = blockIdx.x;
    acc[threadIdx.x] = 0.f;
    __syncthreads();
    int a = start[(size_t)b * GWG];
    int e = (b + 1 < nbuck) ? start[(size_t)(b + 1) * GWG] : E;
    for (int j = a + threadIdx.x; j < e; j += NPB) {
        unsigned rec = (unsigned)binned[j];
        atomicAdd(&acc[rec >> SHIFT], px[rec & SMASK]);
    }
    __syncthreads();
    int node = (b << LB) + threadIdx.x;
    if (node < N) {
        float dv = dis[node];
        float av = dv * (acc[threadIdx.x] + px[node]);
        float hx = fmaxf(fmaf(av, W1[0], b1[0]), 0.f) * dv;
        float hy = fmaxf(fmaf(av, W1[1], b1[1]), 0.f) * dv;
        float hz = fmaxf(fmaf(av, W1[2], b1[2]), 0.f) * dv;
        float hw = fmaxf(fmaf(av, W1[3], b1[3]), 0.f) * dv;
        __half2 lo = __floats2half2_rn(hx, hy);
        __half2 hi = __floats2half2_rn(hz, hw);
        uint2 r;
        r.x = *(unsigned int*)&lo;
        r.y = *(unsigned int*)&hi;
        h1s[node] = r;
    }
}

// layer2: pt = (relu(dis*(acc+self)@W2+b2)@W3)*dis
// fixed-point packed u64 LDS atomics: 2 ds_add_u64 per edge (validated R16).
__global__ void k_g4(const int* __restrict__ start, const int* __restrict__ binned,
                     const uint2* __restrict__ h1s, const float* __restrict__ dis,
                     const float* __restrict__ W2, const float* __restrict__ b2,
                     const float* __restrict__ W3, float* __restrict__ pt,
                     int N, int E, int nbuck) {
    __shared__ unsigned long long accA[NPB];  // feat0 (lo32) | feat1 (hi32)
    __shared__ unsigned long long accB[NPB];  // feat2 (lo32) | feat3 (hi32)
    int b = blockIdx.x;
    accA[threadIdx.x] = 0ull;
    accB[threadIdx.x] = 0ull;
    __syncthreads();
    int a = start[(size_t)b * GWG];
    int e = (b + 1 < nbuck) ? start[(size_t)(b + 1) * GWG] : E;
    int j = a + threadIdx.x;
    for (; j + NPB < e; j += 2 * NPB) {
        unsigned r0 = (unsigned)binned[j];
        unsigned r1 = (unsigned)binned[j + NPB];
        uint2 q0 = h1s[r0 & SMASK];
        uint2 q1 = h1s[r1 & SMASK];
        float2 a01 = __half22float2(*(__half2*)&q0.x);
        float2 a23 = __half22float2(*(__half2*)&q0.y);
        float2 c01 = __half22float2(*(__half2*)&q1.x);
        float2 c23 = __half22float2(*(__half2*)&q1.y);
        int l0 = (int)(r0 >> SHIFT);
        int l1 = (int)(r1 >> SHIFT);
        unsigned long long pA0 = (unsigned long long)(unsigned)(a01.x * FSCALE)
                               | ((unsigned long long)(unsigned)(a01.y * FSCALE) << 32);
        unsigned long long pB0 = (unsigned long long)(unsigned)(a23.x * FSCALE)
                               | ((unsigned long long)(unsigned)(a23.y * FSCALE) << 32);
        unsigned long long pA1 = (unsigned long long)(unsigned)(c01.x * FSCALE)
                               | ((unsigned long long)(unsigned)(c01.y * FSCALE) << 32);
        unsigned long long pB1 = (unsigned long long)(unsigned)(c23.x * FSCALE)
                               | ((unsigned long long)(unsigned)(c23.y * FSCALE) << 32);
        atomicAdd(&accA[l0], pA0);
        atomicAdd(&accB[l0], pB0);
        atomicAdd(&accA[l1], pA1);
        atomicAdd(&accB[l1], pB1);
    }
    if (j < e) {
        unsigned r0 = (unsigned)binned[j];
        uint2 q0 = h1s[r0 & SMASK];
        float2 a01 = __half22float2(*(__half2*)&q0.x);
        float2 a23 = __half22float2(*(__half2*)&q0.y);
        int l0 = (int)(r0 >> SHIFT);
        unsigned long long pA0 = (unsigned long long)(unsigned)(a01.x * FSCALE)
                               | ((unsigned long long)(unsigned)(a01.y * FSCALE) << 32);
        unsigned long long pB0 = (unsigned long long)(unsigned)(a23.x * FSCALE)
                               | ((unsigned long long)(unsigned)(a23.y * FSCALE) << 32);
        atomicAdd(&accA[l0], pA0);
        atomicAdd(&accB[l0], pB0);
    }
    __syncthreads();
    int node = (b << LB) + threadIdx.x;
    if (node < N) {
        uint2 hs = h1s[node];
        float2 s01 = __half22float2(*(__half2*)&hs.x);
        float2 s23 = __half22float2(*(__half2*)&hs.y);
        unsigned long long rA = accA[threadIdx.x];
        unsigned long long rB = accB[threadIdx.x];
        float dv = dis[node];
        float v0 = dv * ((float)(unsigned)(rA)        * FINV + s01.x);
        float v1 = dv * ((float)(unsigned)(rA >> 32)  * FINV + s01.y);
        float v2 = dv * ((float)(unsigned)(rB)        * FINV + s23.x);
        float v3 = dv * ((float)(unsigned)(rB >> 32)  * FINV + s23.y);
        float a0 = fmaxf(v0 * W2[0] + v1 * W2[4] + v2 * W2[8]  + v3 * W2[12] + b2[0], 0.f);
        float a1 = fmaxf(v0 * W2[1] + v1 * W2[5] + v2 * W2[9]  + v3 * W2[13] + b2[1], 0.f);
        float a2 = fmaxf(v0 * W2[2] + v1 * W2[6] + v2 * W2[10] + v3 * W2[14] + b2[2], 0.f);
        float a3 = fmaxf(v0 * W2[3] + v1 * W2[7] + v2 * W2[11] + v3 * W2[15] + b2[3], 0.f);
        pt[node] = (a0 * W3[0] + a1 * W3[1] + a2 * W3[2] + a3 * W3[3]) * dv;
    }
}

// layer3 + fused global_add_pool
__global__ void k_g3f(const int* __restrict__ start, const int* __restrict__ binned,
                      const float* __restrict__ pt, const float* __restrict__ dis,
                      const int* __restrict__ batch, const float* __restrict__ b3,
                      float* __restrict__ out, int N, int E, int nbuck) {
    __shared__ float acc[NPB];
    __shared__ float g[NGRAPH];
    int b = blockIdx.x;
    acc[threadIdx.x] = 0.f;
    if (threadIdx.x < NGRAPH) g[threadIdx.x] = 0.f;
    __syncthreads();
    int a = start[(size_t)b * GWG];
    int e = (b + 1 < nbuck) ? start[(size_t)(b + 1) * GWG] : E;
    for (int j = a + threadIdx.x; j < e; j += NPB)
    {
        unsigned rec = (unsigned)binned[j];
        atomicAdd(&acc[rec >> SHIFT], pt[rec & SMASK]);
    }
    __syncthreads();
    int node = (b << LB) + threadIdx.x;
    if (node < N) {
        float y = dis[node] * (acc[threadIdx.x] + pt[node]) + b3[0];
        atomicAdd(&g[batch[node]], y);
    }
    __syncthreads();
    if (threadIdx.x < NGRAPH) {
        float v = g[threadIdx.x];
        if (v != 0.f) atomicAdd(out + threadIdx.x, v);
    }
}

// ===================== fallback: validated R2 CSR path =====================

__global__ void k_hist(const int* __restrict__ dst, int* __restrict__ deg, int E) {
    int tid = blockIdx.x * blockDim.x + threadIdx.x;
    int st  = gridDim.x * blockDim.x;
    int E4  = E >> 2;
    const int4* d4 = (const int4*)dst;
    for (int i = tid; i < E4; i += st) {
        int4 d = d4[i];
        atomicAdd(deg + d.x, 1);
        atomicAdd(deg + d.y, 1);
        atomicAdd(deg + d.z, 1);
        atomicAdd(deg + d.w, 1);
    }
    for (int i = (E4 << 2) + tid; i < E; i += st) atomicAdd(deg + dst[i], 1);
}

__global__ void k_scan1(const int* __restrict__ deg, int* __restrict__ bsum, int N) {
    __shared__ int sh[SCAN_T];
    int base = blockIdx.x * SCAN_B + threadIdx.x * SCAN_V;
    int s = 0;
#pragma unroll
    for (int k = 0; k < SCAN_V; ++k) {
        int idx = base + k;
        if (idx < N) s += deg[idx];
    }
    sh[threadIdx.x] = s;
    __syncthreads();
    for (int o = SCAN_T / 2; o > 0; o >>= 1) {
        if (threadIdx.x < o) sh[threadIdx.x] += sh[threadIdx.x + o];
        __syncthreads();
    }
    if (threadIdx.x == 0) bsum[blockIdx.x] = sh[0];
}

__global__ void k_scan2(int* __restrict__ bsum, int nb) {
    __shared__ int sh[1024];
    int t = threadIdx.x;
    int v = (t < nb) ? bsum[t] : 0;
    sh[t] = v;
    __syncthreads();
    for (int o = 1; o < 1024; o <<= 1) {
        int u = (t >= o) ? sh[t - o] : 0;
        __syncthreads();
        sh[t] += u;
        __syncthreads();
    }
    if (t < nb) bsum[t] = sh[t] - v;
}

__global__ void k_scan3(const int* __restrict__ deg, const int* __restrict__ bsum,
                        const float* __restrict__ x,
                        int* __restrict__ off, int* __restrict__ cur,
                        float* __restrict__ dis, float* __restrict__ px,
                        int N, int E) {
    __shared__ int sh[SCAN_T];
    int t = threadIdx.x;
    int base = blockIdx.x * SCAN_B + t * SCAN_V;
    int d[SCAN_V];
    int s = 0;
#pragma unroll
    for (int k = 0; k < SCAN_V; ++k) {
        int idx = base + k;
        d[k] = (idx < N) ? deg[idx] : 0;
        s += d[k];
    }
    sh[t] = s;
    __syncthreads();
    for (int o = 1; o < SCAN_T; o <<= 1) {
        int u = (t >= o) ? sh[t - o] : 0;
        __syncthreads();
        sh[t] += u;
        __syncthreads();
    }
    int run = bsum[blockIdx.x] + sh[t] - s;
#pragma unroll
    for (int k = 0; k < SCAN_V; ++k) {
        int idx = base + k;
        if (idx < N) {
            off[idx] = run;
            cur[idx] = run;
            float dv = rsqrtf((float)d[k] + 1.0f);
            dis[idx] = dv;
            px[idx]  = x[idx] * dv;
            run += d[k];
        }
    }
    if (blockIdx.x == 0 && t == 0) off[N] = E;
}

__global__ void k_build(const int* __restrict__ src, const int* __restrict__ dst,
                        int* __restrict__ cur, int* __restrict__ csr, int E) {
    int tid = blockIdx.x * blockDim.x + threadIdx.x;
    int st  = gridDim.x * blockDim.x;
    int E4  = E >> 2;
    const int4* s4 = (const int4*)src;
    const int4* d4 = (const int4*)dst;
    for (int i = tid; i < E4; i += st) {
        int4 s = s4[i];
        int4 d = d4[i];
        csr[atomicAdd(cur + d.x, 1)] = s.x;
        csr[atomicAdd(cur + d.y, 1)] = s.y;
        csr[atomicAdd(cur + d.z, 1)] = s.z;
        csr[atomicAdd(cur + d.w, 1)] = s.w;
    }
    for (int i = (E4 << 2) + tid; i < E; i += st)
        csr[atomicAdd(cur + dst[i], 1)] = src[i];
}

__global__ void k_gnode1(const int* __restrict__ off, const int* __restrict__ csr,
                         const float* __restrict__ px, const float* __restrict__ dis,
                         const float* __restrict__ W1, const float* __restrict__ b1,
                         float4* __restrict__ h1s, int N) {
    float w0 = W1[0], w1 = W1[1], w2 = W1[2], w3 = W1[3];
    float c0 = b1[0], c1 = b1[1], c2 = b1[2], c3 = b1[3];
    int i = blockIdx.x * blockDim.x + threadIdx.x;
    if (i >= N) return;
    int a = off[i], b = off[i + 1];
    float s = 0.f;
    for (int j = a; j < b; ++j) s += px[csr[j]];
    float dv = dis[i];
    float av = dv * (s + px[i]);
    float4 h;
    h.x = fmaxf(fmaf(av, w0, c0), 0.f) * dv;
    h.y = fmaxf(fmaf(av, w1, c1), 0.f) * dv;
    h.z = fmaxf(fmaf(av, w2, c2), 0.f) * dv;
    h.w = fmaxf(fmaf(av, w3, c3), 0.f) * dv;
    h1s[i] = h;
}

__global__ void k_gnode2(const int* __restrict__ off, const int* __restrict__ csr,
                         const float4* __restrict__ h1s, const float* __restrict__ dis,
                         const float* __restrict__ W2, const float* __restrict__ b2,
                         const float* __restrict__ W3, float* __restrict__ pt, int N) {
    float w[16];
#pragma unroll
    for (int k = 0; k < 16; ++k) w[k] = W2[k];
    float c0 = b2[0], c1 = b2[1], c2 = b2[2], c3 = b2[3];
    float u0 = W3[0], u1 = W3[1], u2 = W3[2], u3 = W3[3];
    int i = blockIdx.x * blockDim.x + threadIdx.x;
    if (i >= N) return;
    int a = off[i], b = off[i + 1];
    float s0 = 0.f, s1 = 0.f, s2 = 0.f, s3 = 0.f;
    for (int j = a; j < b; ++j) {
        float4 h = h1s[csr[j]];
        s0 += h.x; s1 += h.y; s2 += h.z; s3 += h.w;
    }
    float4 hs = h1s[i];
    float dv = dis[i];
    float v0 = dv * (s0 + hs.x);
    float v1 = dv * (s1 + hs.y);
    float v2 = dv * (s2 + hs.z);
    float v3 = dv * (s3 + hs.w);
    float a0 = fmaxf(v0 * w[0] + v1 * w[4] + v2 * w[8]  + v3 * w[12] + c0, 0.f);
    float a1 = fmaxf(v0 * w[1] + v1 * w[5] + v2 * w[9]  + v3 * w[13] + c1, 0.f);
    float a2 = fmaxf(v0 * w[2] + v1 * w[6] + v2 * w[10] + v3 * w[14] + c2, 0.f);
    float a3 = fmaxf(v0 * w[3] + v1 * w[7] + v2 * w[11] + v3 * w[15] + c3, 0.f);
    pt[i] = (a0 * u0 + a1 * u1 + a2 * u2 + a3 * u3) * dv;
}

__global__ void k_gpool(const int* __restrict__ off, const int* __restrict__ csr,
                        const float* __restrict__ pt, const float* __restrict__ dis,
                        const int* __restrict__ batch, const float* __restrict__ b3,
                        float* __restrict__ out, int N) {
    __shared__ float g[NGRAPH];
    for (int j = threadIdx.x; j < NGRAPH; j += blockDim.x) g[j] = 0.f;
    __syncthreads();
    int i = blockIdx.x * blockDim.x + threadIdx.x;
    if (i < N) {
        int a = off[i], b = off[i + 1];
        float s = 0.f;
        for (int j = a; j < b; ++j) s += pt[csr[j]];
        float v = dis[i] * (s + pt[i]) + b3[0];
        atomicAdd(&g[batch[i]], v);
    }
    __syncthreads();
    for (int j = threadIdx.x; j < NGRAPH; j += blockDim.x) {
        float v = g[j];
        if (v != 0.f) atomicAdd(out + j, v);
    }
}

// ===================== launch =====================

extern "C" void kernel_launch(void* const* d_in, const int* in_sizes, int n_in,
                              void* d_out, int out_size, void* d_ws, size_t ws_size,
                              hipStream_t stream) {
    const float* x     = (const float*)d_in[0];
    const int*   ei    = (const int*)d_in[1];
    const int*   batch = (const int*)d_in[2];
    const float* W1 = (const float*)d_in[3];
    const float* b1 = (const float*)d_in[4];
    const float* W2 = (const float*)d_in[5];
    const float* b2 = (const float*)d_in[6];
    const float* W3 = (const float*)d_in[7];
    const float* b3 = (const float*)d_in[8];

    int N = in_sizes[0];
    int E = in_sizes[1] / 2;
    const int* src = ei;
    const int* dst = ei + E;

    const int blk = 256;
    int nbuck = (N + NPB - 1) >> LB;
    size_t M  = (size_t)nbuck * GWG;                 // cnt/start matrix elems
    int chunk = (int)(((E + GWG - 1) / GWG + 3) & ~3);
    int nblk  = (int)((M + SCAN_B - 1) / SCAN_B);

    size_t Np = ((size_t)N + 4 + 3) & ~(size_t)3;    // >= N+1, multiple of 4
    size_t part_need = (2 * M + 2048 + 6 * Np + (size_t)E) * sizeof(int);

    hipMemsetAsync(d_out, 0, (size_t)out_size * sizeof(float), stream);

    if (N < (1 << SHIFT) && nbuck <= MAXB && nblk <= 1024 && ws_size >= part_need) {
        // ---- two-pass partition path ----
        int*   cnt    = (int*)d_ws;                  // [M]
        int*   startm = cnt + M;                     // [M]
        int*   bs     = startm + M;                  // [2048]
        float* dis    = (float*)(bs + 2048);         // [Np]
        float* pxpt   = dis + Np;                    // [Np]  px for L1, then pt for L3
        uint2* h1s    = (uint2*)(pxpt + Np);         // [Np]  fp16x4 per node (8B)
        int*   binned = (int*)(h1s + Np);            // [E]

        k_p1 <<<GWG, blk, 0, stream>>>(dst, cnt, E, chunk, nbuck);
        k_sA <<<nblk, SCAN_T, 0, stream>>>(cnt, bs, (int)M);
        k_sB <<<1, 1024, 0, stream>>>(bs, nblk);
        k_sC <<<nblk, SCAN_T, 0, stream>>>(cnt, bs, startm, (int)M);
        k_p2 <<<GWG, blk, 0, stream>>>(src, dst, startm, binned, E, chunk, nbuck);
        k_boff<<<nbuck, NPB, 0, stream>>>(startm, binned, x, dis, pxpt, N, E, nbuck);
        k_g1 <<<nbuck, NPB, 0, stream>>>(startm, binned, pxpt, dis, W1, b1,
                                         h1s, N, E, nbuck);
        k_g4 <<<nbuck, NPB, 0, stream>>>(startm, binned, (const uint2*)h1s, dis,
                                         W2, b2, W3, pxpt, N, E, nbuck);
        k_g3f<<<nbuck, NPB, 0, stream>>>(startm, binned, pxpt, dis, batch, b3,
                                         (float*)d_out, N, E, nbuck);
    } else {
        // ---- fallback: R2 CSR gather path ----
        int*   deg  = (int*)d_ws;
        int*   off  = deg + Np;
        int*   cur  = off + Np;
        float* dis  = (float*)(cur + Np);
        float* px   = dis + Np;
        float* pt   = px + Np;
        int*   bsum = (int*)(pt + Np);
        float* h1s  = (float*)(bsum + Np);
        int*   csr  = (int*)(h1s + 4 * Np);

        hipMemsetAsync(deg, 0, Np * sizeof(int), stream);

        int nb    = (N + SCAN_B - 1) / SCAN_B;
        int ngrid = (N + blk - 1) / blk;
        int egrid = 8192;

        k_hist <<<egrid, blk, 0, stream>>>(dst, deg, E);
        k_scan1<<<nb, SCAN_T, 0, stream>>>(deg, bsum, N);
        k_scan2<<<1, 1024, 0, stream>>>(bsum, nb);
        k_scan3<<<nb, SCAN_T, 0, stream>>>(deg, bsum, x, off, cur, dis, px, N, E);
        k_build<<<egrid, blk, 0, stream>>>(src, dst, cur, csr, E);
        k_gnode1<<<ngrid, blk, 0, stream>>>(off, csr, px, dis, W1, b1, (float4*)h1s, N);
        k_gnode2<<<ngrid, blk, 0, stream>>>(off, csr, (const float4*)h1s, dis, W2, b2, W3, pt, N);
        k_gpool <<<ngrid, blk, 0, stream>>>(off, csr, pt, dis, batch, b3, (float*)d_out, N);
    }
}

// Round 19
// 402.468 us; speedup vs baseline: 1.3554x; 1.3554x over previous
//
#include <hip/hip_runtime.h>
#include <hip/hip_fp16.h>

#define NGRAPH 512
#define SCAN_T 256
#define SCAN_V 4
#define SCAN_B (SCAN_T * SCAN_V)

// bucket scheme: 1024 nodes per bucket, two-pass WG-private radix partition.
#define LB 10
#define NPB 1024
#define SHIFT 22
#define SMASK ((1 << SHIFT) - 1)
#define MAXB 512
#define GWG 512   // workgroups in partition passes

#define TILE 4096
#define TPB 256
#define EPT (TILE / TPB)   // 16 edges per thread per tile

#define FSCALE 16777216.0f          // 2^24 fixed-point scale
#define FINV   (1.0f / 16777216.0f)

// ===================== two-pass partition =====================

// pass1: per-WG LDS bucket histogram over private chunk -> cnt[bucket][GWG]
__global__ void k_p1(const int* __restrict__ dst, int* __restrict__ cnt,
                     int E, int chunk, int nbuck) {
    __shared__ int hist[MAXB];
    int w = blockIdx.x;
    for (int i = threadIdx.x; i < nbuck; i += blockDim.x) hist[i] = 0;
    __syncthreads();
    int beg = w * chunk;
    int end = min(beg + chunk, E);
    if (beg < end) {
        if ((((uintptr_t)(dst + beg)) & 15) == 0) {
            const int4* d4 = (const int4*)(dst + beg);
            int n4 = (end - beg) >> 2;
            for (int i = threadIdx.x; i < n4; i += blockDim.x) {
                int4 d = d4[i];
                atomicAdd(&hist[d.x >> LB], 1);
                atomicAdd(&hist[d.y >> LB], 1);
                atomicAdd(&hist[d.z >> LB], 1);
                atomicAdd(&hist[d.w >> LB], 1);
            }
            for (int i = beg + (n4 << 2) + threadIdx.x; i < end; i += blockDim.x)
                atomicAdd(&hist[dst[i] >> LB], 1);
        } else {
            for (int i = beg + threadIdx.x; i < end; i += blockDim.x)
                atomicAdd(&hist[dst[i] >> LB], 1);
        }
    }
    __syncthreads();
    for (int b = threadIdx.x; b < nbuck; b += blockDim.x)
        cnt[(size_t)b * GWG + w] = hist[b];
}

// scanA: per-block (1024-elem) sums of cnt -> bs
__global__ void k_sA(const int* __restrict__ cnt, int* __restrict__ bs, int M) {
    __shared__ int sh[SCAN_T];
    int base = blockIdx.x * SCAN_B + threadIdx.x * SCAN_V;
    int s = 0;
#pragma unroll
    for (int k = 0; k < SCAN_V; ++k) {
        int idx = base + k;
        if (idx < M) s += cnt[idx];
    }
    sh[threadIdx.x] = s;
    __syncthreads();
    for (int o = SCAN_T / 2; o > 0; o >>= 1) {
        if (threadIdx.x < o) sh[threadIdx.x] += sh[threadIdx.x + o];
        __syncthreads();
    }
    if (threadIdx.x == 0) bs[blockIdx.x] = sh[0];
}

// scanB: single block, 1024 threads: exclusive scan of bs[0..nb)
__global__ void k_sB(int* __restrict__ bs, int nb) {
    __shared__ int sh[1024];
    int t = threadIdx.x;
    int v = (t < nb) ? bs[t] : 0;
    sh[t] = v;
    __syncthreads();
    for (int o = 1; o < 1024; o <<= 1) {
        int u = (t >= o) ? sh[t - o] : 0;
        __syncthreads();
        sh[t] += u;
        __syncthreads();
    }
    if (t < nb) bs[t] = sh[t] - v;
}

// scanC: full exclusive scan -> start[bucket][GWG]
__global__ void k_sC(const int* __restrict__ cnt, const int* __restrict__ bs,
                     int* __restrict__ start, int M) {
    __shared__ int sh[SCAN_T];
    int t = threadIdx.x;
    int base = blockIdx.x * SCAN_B + t * SCAN_V;
    int v[SCAN_V];
    int s = 0;
#pragma unroll
    for (int k = 0; k < SCAN_V; ++k) {
        int idx = base + k;
        v[k] = (idx < M) ? cnt[idx] : 0;
        s += v[k];
    }
    sh[t] = s;
    __syncthreads();
    for (int o = 1; o < SCAN_T; o <<= 1) {
        int u = (t >= o) ? sh[t - o] : 0;
        __syncthreads();
        sh[t] += u;
        __syncthreads();
    }
    int run = bs[blockIdx.x] + sh[t] - s;
#pragma unroll
    for (int k = 0; k < SCAN_V; ++k) {
        int idx = base + k;
        if (idx < M) {
            start[idx] = run;
            run += v[k];
        }
    }
}

// pass2: per-tile LDS counting sort, then bucket-grouped contiguous writes.
// Each (wg,bucket) output line fills within 1-2 adjacent tiles (microseconds)
// so L2 coalesces full 64B lines before writeback — kills write amplification.
__global__ void k_p2(const int* __restrict__ src, const int* __restrict__ dst,
                     const int* __restrict__ start, int* __restrict__ binned,
                     int E, int chunk, int nbuck) {
    __shared__ int   cur[MAXB];
    __shared__ int   hist[MAXB];
    __shared__ int   off[MAXB];
    __shared__ int   pl[MAXB];
    __shared__ int   sc0[MAXB];
    __shared__ int   sc1[MAXB];
    __shared__ int   buf[TILE];
    __shared__ short bkt[TILE];
    int tid = threadIdx.x;
    int w = blockIdx.x;
    for (int b = tid; b < nbuck; b += TPB) cur[b] = start[(size_t)b * GWG + w];
    __syncthreads();
    int beg = w * chunk;
    int end = min(beg + chunk, E);
    for (int t0 = beg; t0 < end; t0 += TILE) {
        int tcnt = min(TILE, end - t0);
        for (int b = tid; b < nbuck; b += TPB) hist[b] = 0;
        __syncthreads();
        // phase 1: load (coalesced) + tile histogram
        int   r[EPT];
        short bb[EPT];
#pragma unroll
        for (int k = 0; k < EPT; ++k) {
            int i = t0 + k * TPB + tid;
            if (i < end) {
                int s = src[i], d = dst[i];
                bb[k] = (short)(d >> LB);
                r[k]  = ((d & (NPB - 1)) << SHIFT) | s;
                atomicAdd(&hist[(int)bb[k]], 1);
            } else {
                bb[k] = -1;
            }
        }
        __syncthreads();
        // inclusive scan of hist over MAXB (Hillis-Steele, double buffer)
        for (int i = tid; i < MAXB; i += TPB) sc0[i] = (i < nbuck) ? hist[i] : 0;
        __syncthreads();
        int* pa = sc0;
        int* pb = sc1;
        for (int o = 1; o < MAXB; o <<= 1) {
            for (int i = tid; i < MAXB; i += TPB)
                pb[i] = pa[i] + ((i >= o) ? pa[i - o] : 0);
            __syncthreads();
            int* tmp = pa; pa = pb; pb = tmp;
        }
        for (int i = tid; i < nbuck; i += TPB) {
            int ex = pa[i] - hist[i];
            off[i] = ex;
            pl[i]  = ex;
        }
        __syncthreads();
        // phase 2: place into LDS grouped by bucket
#pragma unroll
        for (int k = 0; k < EPT; ++k) {
            if (bb[k] >= 0) {
                int pos = atomicAdd(&pl[(int)bb[k]], 1);
                buf[pos] = r[k];
                bkt[pos] = bb[k];
            }
        }
        __syncthreads();
        // phase 3: bucket-grouped contiguous global writes
        for (int p = tid; p < tcnt; p += TPB) {
            int b = (int)bkt[p];
            binned[cur[b] + (p - off[b])] = buf[p];
        }
        __syncthreads();
        for (int b = tid; b < nbuck; b += TPB) cur[b] += hist[b];
        __syncthreads();
    }
}

// ===================== per-bucket layers (LDS accumulators, 1024-thr blocks) ===

// degree hist -> dis, px
__global__ void k_boff(const int* __restrict__ start, const int* __restrict__ binned,
                       const float* __restrict__ x, float* __restrict__ dis,
                       float* __restrict__ px, int N, int E, int nbuck) {
    __shared__ int hist[NPB];
    int b = blockIdx.x;
    hist[threadIdx.x] = 0;
    __syncthreads();
    int a = start[(size_t)b * GWG];
    int e = (b + 1 < nbuck) ? start[(size_t)(b + 1) * GWG] : E;
    for (int j = a + threadIdx.x; j < e; j += NPB)
        atomicAdd(&hist[((unsigned)binned[j]) >> SHIFT], 1);
    __syncthreads();
    int node = (b << LB) + threadIdx.x;
    if (node < N) {
        float dv = rsqrtf((float)hist[threadIdx.x] + 1.0f);
        dis[node] = dv;
        px[node]  = x[node] * dv;
    }
}

// layer1: h1s(fp16x4) = relu(dis*(acc+px)*W1+b1)*dis
__global__ void k_g1(const int* __restrict__ start, const int* __restrict__ binned,
                     const float* __restrict__ px, const float* __restrict__ dis,
                     const float* __restrict__ W1, const float* __restrict__ b1,
                     uint2* __restrict__ h1s, int N, int E, int nbuck) {
    __shared__ float acc[NPB];
    int b = blockIdx.x;
    acc[threadIdx.x] = 0.f;
    __syncthreads();
    int a = start[(size_t)b * GWG];
    int e = (b + 1 < nbuck) ? start[(size_t)(b + 1) * GWG] : E;
    for (int j = a + threadIdx.x; j < e; j += NPB) {
        unsigned rec = (unsigned)binned[j];
        atomicAdd(&acc[rec >> SHIFT], px[rec & SMASK]);
    }
    __syncthreads();
    int node = (b << LB) + threadIdx.x;
    if (node < N) {
        float dv = dis[node];
        float av = dv * (acc[threadIdx.x] + px[node]);
        float hx = fmaxf(fmaf(av, W1[0], b1[0]), 0.f) * dv;
        float hy = fmaxf(fmaf(av, W1[1], b1[1]), 0.f) * dv;
        float hz = fmaxf(fmaf(av, W1[2], b1[2]), 0.f) * dv;
        float hw = fmaxf(fmaf(av, W1[3], b1[3]), 0.f) * dv;
        __half2 lo = __floats2half2_rn(hx, hy);
        __half2 hi = __floats2half2_rn(hz, hw);
        uint2 r;
        r.x = *(unsigned int*)&lo;
        r.y = *(unsigned int*)&hi;
        h1s[node] = r;
    }
}

__device__ __forceinline__ void unpack_h4(uint2 r, float& f0, float& f1,
                                          float& f2, float& f3) {
    __half2 lo = *(__half2*)&r.x;
    __half2 hi = *(__half2*)&r.y;
    float2 a = __half22float2(lo);
    float2 b = __half22float2(hi);
    f0 = a.x; f1 = a.y; f2 = b.x; f3 = b.y;
}

// layer2: pt = (relu(dis*(acc+self)@W2+b2)@W3)*dis
// fixed-point packed u64 LDS atomics: 2 ds_add_u64 per edge (validated R16).
__global__ void k_g4(const int* __restrict__ start, const int* __restrict__ binned,
                     const uint2* __restrict__ h1s, const float* __restrict__ dis,
                     const float* __restrict__ W2, const float* __restrict__ b2,
                     const float* __restrict__ W3, float* __restrict__ pt,
                     int N, int E, int nbuck) {
    __shared__ unsigned long long accA[NPB];  // feat0 (lo32) | feat1 (hi32)
    __shared__ unsigned long long accB[NPB];  // feat2 (lo32) | feat3 (hi32)
    int b = blockIdx.x;
    accA[threadIdx.x] = 0ull;
    accB[threadIdx.x] = 0ull;
    __syncthreads();
    int a = start[(size_t)b * GWG];
    int e = (b + 1 < nbuck) ? start[(size_t)(b + 1) * GWG] : E;
    int j = a + threadIdx.x;
    for (; j + NPB < e; j += 2 * NPB) {
        unsigned r0 = (unsigned)binned[j];
        unsigned r1 = (unsigned)binned[j + NPB];
        uint2 q0 = h1s[r0 & SMASK];
        uint2 q1 = h1s[r1 & SMASK];
        float2 a01 = __half22float2(*(__half2*)&q0.x);
        float2 a23 = __half22float2(*(__half2*)&q0.y);
        float2 c01 = __half22float2(*(__half2*)&q1.x);
        float2 c23 = __half22float2(*(__half2*)&q1.y);
        int l0 = (int)(r0 >> SHIFT);
        int l1 = (int)(r1 >> SHIFT);
        unsigned long long pA0 = (unsigned long long)(unsigned)(a01.x * FSCALE)
                               | ((unsigned long long)(unsigned)(a01.y * FSCALE) << 32);
        unsigned long long pB0 = (unsigned long long)(unsigned)(a23.x * FSCALE)
                               | ((unsigned long long)(unsigned)(a23.y * FSCALE) << 32);
        unsigned long long pA1 = (unsigned long long)(unsigned)(c01.x * FSCALE)
                               | ((unsigned long long)(unsigned)(c01.y * FSCALE) << 32);
        unsigned long long pB1 = (unsigned long long)(unsigned)(c23.x * FSCALE)
                               | ((unsigned long long)(unsigned)(c23.y * FSCALE) << 32);
        atomicAdd(&accA[l0], pA0);
        atomicAdd(&accB[l0], pB0);
        atomicAdd(&accA[l1], pA1);
        atomicAdd(&accB[l1], pB1);
    }
    if (j < e) {
        unsigned r0 = (unsigned)binned[j];
        uint2 q0 = h1s[r0 & SMASK];
        float2 a01 = __half22float2(*(__half2*)&q0.x);
        float2 a23 = __half22float2(*(__half2*)&q0.y);
        int l0 = (int)(r0 >> SHIFT);
        unsigned long long pA0 = (unsigned long long)(unsigned)(a01.x * FSCALE)
                               | ((unsigned long long)(unsigned)(a01.y * FSCALE) << 32);
        unsigned long long pB0 = (unsigned long long)(unsigned)(a23.x * FSCALE)
                               | ((unsigned long long)(unsigned)(a23.y * FSCALE) << 32);
        atomicAdd(&accA[l0], pA0);
        atomicAdd(&accB[l0], pB0);
    }
    __syncthreads();
    int node = (b << LB) + threadIdx.x;
    if (node < N) {
        uint2 hs = h1s[node];
        float2 s01 = __half22float2(*(__half2*)&hs.x);
        float2 s23 = __half22float2(*(__half2*)&hs.y);
        unsigned long long rA = accA[threadIdx.x];
        unsigned long long rB = accB[threadIdx.x];
        float dv = dis[node];
        float v0 = dv * ((float)(unsigned)(rA)        * FINV + s01.x);
        float v1 = dv * ((float)(unsigned)(rA >> 32)  * FINV + s01.y);
        float v2 = dv * ((float)(unsigned)(rB)        * FINV + s23.x);
        float v3 = dv * ((float)(unsigned)(rB >> 32)  * FINV + s23.y);
        float a0 = fmaxf(v0 * W2[0] + v1 * W2[4] + v2 * W2[8]  + v3 * W2[12] + b2[0], 0.f);
        float a1 = fmaxf(v0 * W2[1] + v1 * W2[5] + v2 * W2[9]  + v3 * W2[13] + b2[1], 0.f);
        float a2 = fmaxf(v0 * W2[2] + v1 * W2[6] + v2 * W2[10] + v3 * W2[14] + b2[2], 0.f);
        float a3 = fmaxf(v0 * W2[3] + v1 * W2[7] + v2 * W2[11] + v3 * W2[15] + b2[3], 0.f);
        pt[node] = (a0 * W3[0] + a1 * W3[1] + a2 * W3[2] + a3 * W3[3]) * dv;
    }
}

// layer3 + fused global_add_pool
__global__ void k_g3f(const int* __restrict__ start, const int* __restrict__ binned,
                      const float* __restrict__ pt, const float* __restrict__ dis,
                      const int* __restrict__ batch, const float* __restrict__ b3,
                      float* __restrict__ out, int N, int E, int nbuck) {
    __shared__ float acc[NPB];
    __shared__ float g[NGRAPH];
    int b = blockIdx.x;
    acc[threadIdx.x] = 0.f;
    if (threadIdx.x < NGRAPH) g[threadIdx.x] = 0.f;
    __syncthreads();
    int a = start[(size_t)b * GWG];
    int e = (b + 1 < nbuck) ? start[(size_t)(b + 1) * GWG] : E;
    for (int j = a + threadIdx.x; j < e; j += NPB)
    {
        unsigned rec = (unsigned)binned[j];
        atomicAdd(&acc[rec >> SHIFT], pt[rec & SMASK]);
    }
    __syncthreads();
    int node = (b << LB) + threadIdx.x;
    if (node < N) {
        float y = dis[node] * (acc[threadIdx.x] + pt[node]) + b3[0];
        atomicAdd(&g[batch[node]], y);
    }
    __syncthreads();
    if (threadIdx.x < NGRAPH) {
        float v = g[threadIdx.x];
        if (v != 0.f) atomicAdd(out + threadIdx.x, v);
    }
}

// ===================== fallback: validated R2 CSR path =====================

__global__ void k_hist(const int* __restrict__ dst, int* __restrict__ deg, int E) {
    int tid = blockIdx.x * blockDim.x + threadIdx.x;
    int st  = gridDim.x * blockDim.x;
    int E4  = E >> 2;
    const int4* d4 = (const int4*)dst;
    for (int i = tid; i < E4; i += st) {
        int4 d = d4[i];
        atomicAdd(deg + d.x, 1);
        atomicAdd(deg + d.y, 1);
        atomicAdd(deg + d.z, 1);
        atomicAdd(deg + d.w, 1);
    }
    for (int i = (E4 << 2) + tid; i < E; i += st) atomicAdd(deg + dst[i], 1);
}

__global__ void k_scan1(const int* __restrict__ deg, int* __restrict__ bsum, int N) {
    __shared__ int sh[SCAN_T];
    int base = blockIdx.x * SCAN_B + threadIdx.x * SCAN_V;
    int s = 0;
#pragma unroll
    for (int k = 0; k < SCAN_V; ++k) {
        int idx = base + k;
        if (idx < N) s += deg[idx];
    }
    sh[threadIdx.x] = s;
    __syncthreads();
    for (int o = SCAN_T / 2; o > 0; o >>= 1) {
        if (threadIdx.x < o) sh[threadIdx.x] += sh[threadIdx.x + o];
        __syncthreads();
    }
    if (threadIdx.x == 0) bsum[blockIdx.x] = sh[0];
}

__global__ void k_scan2(int* __restrict__ bsum, int nb) {
    __shared__ int sh[1024];
    int t = threadIdx.x;
    int v = (t < nb) ? bsum[t] : 0;
    sh[t] = v;
    __syncthreads();
    for (int o = 1; o < 1024; o <<= 1) {
        int u = (t >= o) ? sh[t - o] : 0;
        __syncthreads();
        sh[t] += u;
        __syncthreads();
    }
    if (t < nb) bsum[t] = sh[t] - v;
}

__global__ void k_scan3(const int* __restrict__ deg, const int* __restrict__ bsum,
                        const float* __restrict__ x,
                        int* __restrict__ off, int* __restrict__ cur,
                        float* __restrict__ dis, float* __restrict__ px,
                        int N, int E) {
    __shared__ int sh[SCAN_T];
    int t = threadIdx.x;
    int base = blockIdx.x * SCAN_B + t * SCAN_V;
    int d[SCAN_V];
    int s = 0;
#pragma unroll
    for (int k = 0; k < SCAN_V; ++k) {
        int idx = base + k;
        d[k] = (idx < N) ? deg[idx] : 0;
        s += d[k];
    }
    sh[t] = s;
    __syncthreads();
    for (int o = 1; o < SCAN_T; o <<= 1) {
        int u = (t >= o) ? sh[t - o] : 0;
        __syncthreads();
        sh[t] += u;
        __syncthreads();
    }
    int run = bsum[blockIdx.x] + sh[t] - s;
#pragma unroll
    for (int k = 0; k < SCAN_V; ++k) {
        int idx = base + k;
        if (idx < N) {
            off[idx] = run;
            cur[idx] = run;
            float dv = rsqrtf((float)d[k] + 1.0f);
            dis[idx] = dv;
            px[idx]  = x[idx] * dv;
            run += d[k];
        }
    }
    if (blockIdx.x == 0 && t == 0) off[N] = E;
}

__global__ void k_build(const int* __restrict__ src, const int* __restrict__ dst,
                        int* __restrict__ cur, int* __restrict__ csr, int E) {
    int tid = blockIdx.x * blockDim.x + threadIdx.x;
    int st  = gridDim.x * blockDim.x;
    int E4  = E >> 2;
    const int4* s4 = (const int4*)src;
    const int4* d4 = (const int4*)dst;
    for (int i = tid; i < E4; i += st) {
        int4 s = s4[i];
        int4 d = d4[i];
        csr[atomicAdd(cur + d.x, 1)] = s.x;
        csr[atomicAdd(cur + d.y, 1)] = s.y;
        csr[atomicAdd(cur + d.z, 1)] = s.z;
        csr[atomicAdd(cur + d.w, 1)] = s.w;
    }
    for (int i = (E4 << 2) + tid; i < E; i += st)
        csr[atomicAdd(cur + dst[i], 1)] = src[i];
}

__global__ void k_gnode1(const int* __restrict__ off, const int* __restrict__ csr,
                         const float* __restrict__ px, const float* __restrict__ dis,
                         const float* __restrict__ W1, const float* __restrict__ b1,
                         float4* __restrict__ h1s, int N) {
    float w0 = W1[0], w1 = W1[1], w2 = W1[2], w3 = W1[3];
    float c0 = b1[0], c1 = b1[1], c2 = b1[2], c3 = b1[3];
    int i = blockIdx.x * blockDim.x + threadIdx.x;
    if (i >= N) return;
    int a = off[i], b = off[i + 1];
    float s = 0.f;
    for (int j = a; j < b; ++j) s += px[csr[j]];
    float dv = dis[i];
    float av = dv * (s + px[i]);
    float4 h;
    h.x = fmaxf(fmaf(av, w0, c0), 0.f) * dv;
    h.y = fmaxf(fmaf(av, w1, c1), 0.f) * dv;
    h.z = fmaxf(fmaf(av, w2, c2), 0.f) * dv;
    h.w = fmaxf(fmaf(av, w3, c3), 0.f) * dv;
    h1s[i] = h;
}

__global__ void k_gnode2(const int* __restrict__ off, const int* __restrict__ csr,
                         const float4* __restrict__ h1s, const float* __restrict__ dis,
                         const float* __restrict__ W2, const float* __restrict__ b2,
                         const float* __restrict__ W3, float* __restrict__ pt, int N) {
    float w[16];
#pragma unroll
    for (int k = 0; k < 16; ++k) w[k] = W2[k];
    float c0 = b2[0], c1 = b2[1], c2 = b2[2], c3 = b2[3];
    float u0 = W3[0], u1 = W3[1], u2 = W3[2], u3 = W3[3];
    int i = blockIdx.x * blockDim.x + threadIdx.x;
    if (i >= N) return;
    int a = off[i], b = off[i + 1];
    float s0 = 0.f, s1 = 0.f, s2 = 0.f, s3 = 0.f;
    for (int j = a; j < b; ++j) {
        float4 h = h1s[csr[j]];
        s0 += h.x; s1 += h.y; s2 += h.z; s3 += h.w;
    }
    float4 hs = h1s[i];
    float dv = dis[i];
    float v0 = dv * (s0 + hs.x);
    float v1 = dv * (s1 + hs.y);
    float v2 = dv * (s2 + hs.z);
    float v3 = dv * (s3 + hs.w);
    float a0 = fmaxf(v0 * w[0] + v1 * w[4] + v2 * w[8]  + v3 * w[12] + c0, 0.f);
    float a1 = fmaxf(v0 * w[1] + v1 * w[5] + v2 * w[9]  + v3 * w[13] + c1, 0.f);
    float a2 = fmaxf(v0 * w[2] + v1 * w[6] + v2 * w[10] + v3 * w[14] + c2, 0.f);
    float a3 = fmaxf(v0 * w[3] + v1 * w[7] + v2 * w[11] + v3 * w[15] + c3, 0.f);
    pt[i] = (a0 * u0 + a1 * u1 + a2 * u2 + a3 * u3) * dv;
}

__global__ void k_gpool(const int* __restrict__ off, const int* __restrict__ csr,
                        const float* __restrict__ pt, const float* __restrict__ dis,
                        const int* __restrict__ batch, const float* __restrict__ b3,
                        float* __restrict__ out, int N) {
    __shared__ float g[NGRAPH];
    for (int j = threadIdx.x; j < NGRAPH; j += blockDim.x) g[j] = 0.f;
    __syncthreads();
    int i = blockIdx.x * blockDim.x + threadIdx.x;
    if (i < N) {
        int a = off[i], b = off[i + 1];
        float s = 0.f;
        for (int j = a; j < b; ++j) s += pt[csr[j]];
        float v = dis[i] * (s + pt[i]) + b3[0];
        atomicAdd(&g[batch[i]], v);
    }
    __syncthreads();
    for (int j = threadIdx.x; j < NGRAPH; j += blockDim.x) {
        float v = g[j];
        if (v != 0.f) atomicAdd(out + j, v);
    }
}

// ===================== launch =====================

extern "C" void kernel_launch(void* const* d_in, const int* in_sizes, int n_in,
                              void* d_out, int out_size, void* d_ws, size_t ws_size,
                              hipStream_t stream) {
    const float* x     = (const float*)d_in[0];
    const int*   ei    = (const int*)d_in[1];
    const int*   batch = (const int*)d_in[2];
    const float* W1 = (const float*)d_in[3];
    const float* b1 = (const float*)d_in[4];
    const float* W2 = (const float*)d_in[5];
    const float* b2 = (const float*)d_in[6];
    const float* W3 = (const float*)d_in[7];
    const float* b3 = (const float*)d_in[8];

    int N = in_sizes[0];
    int E = in_sizes[1] / 2;
    const int* src = ei;
    const int* dst = ei + E;

    const int blk = 256;
    int nbuck = (N + NPB - 1) >> LB;
    size_t M  = (size_t)nbuck * GWG;                 // cnt/start matrix elems
    int chunk = (int)(((E + GWG - 1) / GWG + 3) & ~3);
    int nblk  = (int)((M + SCAN_B - 1) / SCAN_B);

    size_t Np = ((size_t)N + 4 + 3) & ~(size_t)3;    // >= N+1, multiple of 4
    size_t part_need = (2 * M + 2048 + 6 * Np + (size_t)E) * sizeof(int);

    hipMemsetAsync(d_out, 0, (size_t)out_size * sizeof(float), stream);

    if (N < (1 << SHIFT) && nbuck <= MAXB && nblk <= 1024 && ws_size >= part_need) {
        // ---- two-pass partition path ----
        int*   cnt    = (int*)d_ws;                  // [M]
        int*   startm = cnt + M;                     // [M]
        int*   bs     = startm + M;                  // [2048]
        float* dis    = (float*)(bs + 2048);         // [Np]
        float* pxpt   = dis + Np;                    // [Np]  px for L1, then pt for L3
        uint2* h1s    = (uint2*)(pxpt + Np);         // [Np]  fp16x4 per node (8B)
        int*   binned = (int*)(h1s + Np);            // [E]

        k_p1 <<<GWG, blk, 0, stream>>>(dst, cnt, E, chunk, nbuck);
        k_sA <<<nblk, SCAN_T, 0, stream>>>(cnt, bs, (int)M);
        k_sB <<<1, 1024, 0, stream>>>(bs, nblk);
        k_sC <<<nblk, SCAN_T, 0, stream>>>(cnt, bs, startm, (int)M);
        k_p2 <<<GWG, TPB, 0, stream>>>(src, dst, startm, binned, E, chunk, nbuck);
        k_boff<<<nbuck, NPB, 0, stream>>>(startm, binned, x, dis, pxpt, N, E, nbuck);
        k_g1 <<<nbuck, NPB, 0, stream>>>(startm, binned, pxpt, dis, W1, b1,
                                         h1s, N, E, nbuck);
        k_g4 <<<nbuck, NPB, 0, stream>>>(startm, binned, (const uint2*)h1s, dis,
                                         W2, b2, W3, pxpt, N, E, nbuck);
        k_g3f<<<nbuck, NPB, 0, stream>>>(startm, binned, pxpt, dis, batch, b3,
                                         (float*)d_out, N, E, nbuck);
    } else {
        // ---- fallback: R2 CSR gather path ----
        int*   deg  = (int*)d_ws;
        int*   off  = deg + Np;
        int*   cur  = off + Np;
        float* dis  = (float*)(cur + Np);
        float* px   = dis + Np;
        float* pt   = px + Np;
        int*   bsum = (int*)(pt + Np);
        float* h1s  = (float*)(bsum + Np);
        int*   csr  = (int*)(h1s + 4 * Np);

        hipMemsetAsync(deg, 0, Np * sizeof(int), stream);

        int nb    = (N + SCAN_B - 1) / SCAN_B;
        int ngrid = (N + blk - 1) / blk;
        int egrid = 8192;

        k_hist <<<egrid, blk, 0, stream>>>(dst, deg, E);
        k_scan1<<<nb, SCAN_T, 0, stream>>>(deg, bsum, N);
        k_scan2<<<1, 1024, 0, stream>>>(bsum, nb);
        k_scan3<<<nb, SCAN_T, 0, stream>>>(deg, bsum, x, off, cur, dis, px, N, E);
        k_build<<<egrid, blk, 0, stream>>>(src, dst, cur, csr, E);
        k_gnode1<<<ngrid, blk, 0, stream>>>(off, csr, px, dis, W1, b1, (float4*)h1s, N);
        k_gnode2<<<ngrid, blk, 0, stream>>>(off, csr, (const float4*)h1s, dis, W2, b2, W3, pt, N);
        k_gpool <<<ngrid, blk, 0, stream>>>(off, csr, pt, dis, batch, b3, (float*)d_out, N);
    }
}

// Round 20
// 388.908 us; speedup vs baseline: 1.4027x; 1.0349x over previous
//
#include <hip/hip_runtime.h>
#include <hip/hip_fp16.h>

#define NGRAPH 512
#define SCAN_T 256
#define SCAN_V 4
#define SCAN_B (SCAN_T * SCAN_V)

// bucket scheme: 1024 nodes per bucket, two-pass WG-private radix partition.
#define LB 10
#define NPB 1024
#define SHIFT 22
#define SMASK ((1 << SHIFT) - 1)
#define MAXB 512
#define GWG 512   // workgroups in partition passes

#define TILE 4096
#define TPB 256
#define EPT (TILE / TPB)   // 16 edges per thread per tile

#define FSCALE 16777216.0f          // 2^24 fixed-point scale
#define FINV   (1.0f / 16777216.0f)

// ===================== two-pass partition =====================

// pass1: per-WG LDS bucket histogram over private chunk -> cnt[bucket][GWG]
__global__ void k_p1(const int* __restrict__ dst, int* __restrict__ cnt,
                     int E, int chunk, int nbuck) {
    __shared__ int hist[MAXB];
    int w = blockIdx.x;
    for (int i = threadIdx.x; i < nbuck; i += blockDim.x) hist[i] = 0;
    __syncthreads();
    int beg = w * chunk;
    int end = min(beg + chunk, E);
    if (beg < end) {
        if ((((uintptr_t)(dst + beg)) & 15) == 0) {
            const int4* d4 = (const int4*)(dst + beg);
            int n4 = (end - beg) >> 2;
            for (int i = threadIdx.x; i < n4; i += blockDim.x) {
                int4 d = d4[i];
                atomicAdd(&hist[d.x >> LB], 1);
                atomicAdd(&hist[d.y >> LB], 1);
                atomicAdd(&hist[d.z >> LB], 1);
                atomicAdd(&hist[d.w >> LB], 1);
            }
            for (int i = beg + (n4 << 2) + threadIdx.x; i < end; i += blockDim.x)
                atomicAdd(&hist[dst[i] >> LB], 1);
        } else {
            for (int i = beg + threadIdx.x; i < end; i += blockDim.x)
                atomicAdd(&hist[dst[i] >> LB], 1);
        }
    }
    __syncthreads();
    for (int b = threadIdx.x; b < nbuck; b += blockDim.x)
        cnt[(size_t)b * GWG + w] = hist[b];
}

// scanA: per-block (1024-elem) sums of cnt -> bs
__global__ void k_sA(const int* __restrict__ cnt, int* __restrict__ bs, int M) {
    __shared__ int sh[SCAN_T];
    int base = blockIdx.x * SCAN_B + threadIdx.x * SCAN_V;
    int s = 0;
#pragma unroll
    for (int k = 0; k < SCAN_V; ++k) {
        int idx = base + k;
        if (idx < M) s += cnt[idx];
    }
    sh[threadIdx.x] = s;
    __syncthreads();
    for (int o = SCAN_T / 2; o > 0; o >>= 1) {
        if (threadIdx.x < o) sh[threadIdx.x] += sh[threadIdx.x + o];
        __syncthreads();
    }
    if (threadIdx.x == 0) bs[blockIdx.x] = sh[0];
}

// scanB: single block, 1024 threads: exclusive scan of bs[0..nb)
__global__ void k_sB(int* __restrict__ bs, int nb) {
    __shared__ int sh[1024];
    int t = threadIdx.x;
    int v = (t < nb) ? bs[t] : 0;
    sh[t] = v;
    __syncthreads();
    for (int o = 1; o < 1024; o <<= 1) {
        int u = (t >= o) ? sh[t - o] : 0;
        __syncthreads();
        sh[t] += u;
        __syncthreads();
    }
    if (t < nb) bs[t] = sh[t] - v;
}

// scanC: full exclusive scan -> start[bucket][GWG]
__global__ void k_sC(const int* __restrict__ cnt, const int* __restrict__ bs,
                     int* __restrict__ start, int M) {
    __shared__ int sh[SCAN_T];
    int t = threadIdx.x;
    int base = blockIdx.x * SCAN_B + t * SCAN_V;
    int v[SCAN_V];
    int s = 0;
#pragma unroll
    for (int k = 0; k < SCAN_V; ++k) {
        int idx = base + k;
        v[k] = (idx < M) ? cnt[idx] : 0;
        s += v[k];
    }
    sh[t] = s;
    __syncthreads();
    for (int o = 1; o < SCAN_T; o <<= 1) {
        int u = (t >= o) ? sh[t - o] : 0;
        __syncthreads();
        sh[t] += u;
        __syncthreads();
    }
    int run = bs[blockIdx.x] + sh[t] - s;
#pragma unroll
    for (int k = 0; k < SCAN_V; ++k) {
        int idx = base + k;
        if (idx < M) {
            start[idx] = run;
            run += v[k];
        }
    }
}

// pass2: per-tile LDS counting sort with shfl wave-scan (2 syncs for the scan
// instead of 18) and 30KB LDS (5 WGs/CU). Bucket-grouped contiguous writes
// keep L2 write coalescing (validated R19).
__global__ void k_p2(const int* __restrict__ src, const int* __restrict__ dst,
                     const int* __restrict__ start, int* __restrict__ binned,
                     int E, int chunk, int nbuck) {
    __shared__ int   cur[MAXB];
    __shared__ int   hist[MAXB];
    __shared__ int   pl[MAXB];
    __shared__ int   wsum[4];
    __shared__ int   buf[TILE];
    __shared__ short bkt[TILE];
    int tid  = threadIdx.x;
    int lane = tid & 63;
    int wave = tid >> 6;
    int w = blockIdx.x;
    for (int b = tid; b < nbuck; b += TPB) cur[b] = start[(size_t)b * GWG + w];
    __syncthreads();
    int beg = w * chunk;
    int end = min(beg + chunk, E);
    for (int t0 = beg; t0 < end; t0 += TILE) {
        int tcnt = min(TILE, end - t0);
        for (int b = tid; b < MAXB; b += TPB) hist[b] = 0;
        __syncthreads();
        // phase 1: load (coalesced) + tile histogram
        int   r[EPT];
        short bb[EPT];
#pragma unroll
        for (int k = 0; k < EPT; ++k) {
            int i = t0 + k * TPB + tid;
            if (i < end) {
                int s = src[i], d = dst[i];
                bb[k] = (short)(d >> LB);
                r[k]  = ((d & (NPB - 1)) << SHIFT) | s;
                atomicAdd(&hist[(int)bb[k]], 1);
            } else {
                bb[k] = -1;
            }
        }
        __syncthreads();
        // exclusive scan of hist[0..MAXB) via per-wave shfl scan, 2 elems/thread
        int e0 = tid * 2, e1 = tid * 2 + 1;
        int v0 = hist[e0], v1 = hist[e1];
        int s = v0 + v1;
        for (int o = 1; o < 64; o <<= 1) {
            int u = __shfl_up(s, o);
            if (lane >= o) s += u;
        }
        if (lane == 63) wsum[wave] = s;
        __syncthreads();
        int ew = 0;
        for (int k = 0; k < wave; ++k) ew += wsum[k];
        int incl1 = ew + s;            // inclusive prefix through e1
        pl[e1] = incl1 - v1;           // exclusive for e1
        pl[e0] = incl1 - v1 - v0;      // exclusive for e0
        __syncthreads();
        // phase 2: place into LDS grouped by bucket
#pragma unroll
        for (int k = 0; k < EPT; ++k) {
            if (bb[k] >= 0) {
                int pos = atomicAdd(&pl[(int)bb[k]], 1);
                buf[pos] = r[k];
                bkt[pos] = bb[k];
            }
        }
        __syncthreads();
        // phase 3: bucket-grouped contiguous global writes
        // (pl now = exclusive + hist, so exclusive offset = pl[b] - hist[b])
        for (int p = tid; p < tcnt; p += TPB) {
            int b = (int)bkt[p];
            int off = pl[b] - hist[b];
            binned[cur[b] + (p - off)] = buf[p];
        }
        __syncthreads();
        for (int b = tid; b < nbuck; b += TPB) cur[b] += hist[b];
        __syncthreads();
    }
}

// ===================== per-bucket layers (LDS accumulators, 1024-thr blocks) ===

// degree hist -> dis, px
__global__ void k_boff(const int* __restrict__ start, const int* __restrict__ binned,
                       const float* __restrict__ x, float* __restrict__ dis,
                       float* __restrict__ px, int N, int E, int nbuck) {
    __shared__ int hist[NPB];
    int b = blockIdx.x;
    hist[threadIdx.x] = 0;
    __syncthreads();
    int a = start[(size_t)b * GWG];
    int e = (b + 1 < nbuck) ? start[(size_t)(b + 1) * GWG] : E;
    for (int j = a + threadIdx.x; j < e; j += NPB)
        atomicAdd(&hist[((unsigned)binned[j]) >> SHIFT], 1);
    __syncthreads();
    int node = (b << LB) + threadIdx.x;
    if (node < N) {
        float dv = rsqrtf((float)hist[threadIdx.x] + 1.0f);
        dis[node] = dv;
        px[node]  = x[node] * dv;
    }
}

// layer1: h1s(fp16x4) = relu(dis*(acc+px)*W1+b1)*dis
__global__ void k_g1(const int* __restrict__ start, const int* __restrict__ binned,
                     const float* __restrict__ px, const float* __restrict__ dis,
                     const float* __restrict__ W1, const float* __restrict__ b1,
                     uint2* __restrict__ h1s, int N, int E, int nbuck) {
    __shared__ float acc[NPB];
    int b = blockIdx.x;
    acc[threadIdx.x] = 0.f;
    __syncthreads();
    int a = start[(size_t)b * GWG];
    int e = (b + 1 < nbuck) ? start[(size_t)(b + 1) * GWG] : E;
    for (int j = a + threadIdx.x; j < e; j += NPB) {
        unsigned rec = (unsigned)binned[j];
        atomicAdd(&acc[rec >> SHIFT], px[rec & SMASK]);
    }
    __syncthreads();
    int node = (b << LB) + threadIdx.x;
    if (node < N) {
        float dv = dis[node];
        float av = dv * (acc[threadIdx.x] + px[node]);
        float hx = fmaxf(fmaf(av, W1[0], b1[0]), 0.f) * dv;
        float hy = fmaxf(fmaf(av, W1[1], b1[1]), 0.f) * dv;
        float hz = fmaxf(fmaf(av, W1[2], b1[2]), 0.f) * dv;
        float hw = fmaxf(fmaf(av, W1[3], b1[3]), 0.f) * dv;
        __half2 lo = __floats2half2_rn(hx, hy);
        __half2 hi = __floats2half2_rn(hz, hw);
        uint2 r;
        r.x = *(unsigned int*)&lo;
        r.y = *(unsigned int*)&hi;
        h1s[node] = r;
    }
}

__device__ __forceinline__ void unpack_h4(uint2 r, float& f0, float& f1,
                                          float& f2, float& f3) {
    __half2 lo = *(__half2*)&r.x;
    __half2 hi = *(__half2*)&r.y;
    float2 a = __half22float2(lo);
    float2 b = __half22float2(hi);
    f0 = a.x; f1 = a.y; f2 = b.x; f3 = b.y;
}

// layer2: pt = (relu(dis*(acc+self)@W2+b2)@W3)*dis
// fixed-point packed u64 LDS atomics: 2 ds_add_u64 per edge (validated R16).
__global__ void k_g4(const int* __restrict__ start, const int* __restrict__ binned,
                     const uint2* __restrict__ h1s, const float* __restrict__ dis,
                     const float* __restrict__ W2, const float* __restrict__ b2,
                     const float* __restrict__ W3, float* __restrict__ pt,
                     int N, int E, int nbuck) {
    __shared__ unsigned long long accA[NPB];  // feat0 (lo32) | feat1 (hi32)
    __shared__ unsigned long long accB[NPB];  // feat2 (lo32) | feat3 (hi32)
    int b = blockIdx.x;
    accA[threadIdx.x] = 0ull;
    accB[threadIdx.x] = 0ull;
    __syncthreads();
    int a = start[(size_t)b * GWG];
    int e = (b + 1 < nbuck) ? start[(size_t)(b + 1) * GWG] : E;
    int j = a + threadIdx.x;
    for (; j + NPB < e; j += 2 * NPB) {
        unsigned r0 = (unsigned)binned[j];
        unsigned r1 = (unsigned)binned[j + NPB];
        uint2 q0 = h1s[r0 & SMASK];
        uint2 q1 = h1s[r1 & SMASK];
        float2 a01 = __half22float2(*(__half2*)&q0.x);
        float2 a23 = __half22float2(*(__half2*)&q0.y);
        float2 c01 = __half22float2(*(__half2*)&q1.x);
        float2 c23 = __half22float2(*(__half2*)&q1.y);
        int l0 = (int)(r0 >> SHIFT);
        int l1 = (int)(r1 >> SHIFT);
        unsigned long long pA0 = (unsigned long long)(unsigned)(a01.x * FSCALE)
                               | ((unsigned long long)(unsigned)(a01.y * FSCALE) << 32);
        unsigned long long pB0 = (unsigned long long)(unsigned)(a23.x * FSCALE)
                               | ((unsigned long long)(unsigned)(a23.y * FSCALE) << 32);
        unsigned long long pA1 = (unsigned long long)(unsigned)(c01.x * FSCALE)
                               | ((unsigned long long)(unsigned)(c01.y * FSCALE) << 32);
        unsigned long long pB1 = (unsigned long long)(unsigned)(c23.x * FSCALE)
                               | ((unsigned long long)(unsigned)(c23.y * FSCALE) << 32);
        atomicAdd(&accA[l0], pA0);
        atomicAdd(&accB[l0], pB0);
        atomicAdd(&accA[l1], pA1);
        atomicAdd(&accB[l1], pB1);
    }
    if (j < e) {
        unsigned r0 = (unsigned)binned[j];
        uint2 q0 = h1s[r0 & SMASK];
        float2 a01 = __half22float2(*(__half2*)&q0.x);
        float2 a23 = __half22float2(*(__half2*)&q0.y);
        int l0 = (int)(r0 >> SHIFT);
        unsigned long long pA0 = (unsigned long long)(unsigned)(a01.x * FSCALE)
                               | ((unsigned long long)(unsigned)(a01.y * FSCALE) << 32);
        unsigned long long pB0 = (unsigned long long)(unsigned)(a23.x * FSCALE)
                               | ((unsigned long long)(unsigned)(a23.y * FSCALE) << 32);
        atomicAdd(&accA[l0], pA0);
        atomicAdd(&accB[l0], pB0);
    }
    __syncthreads();
    int node = (b << LB) + threadIdx.x;
    if (node < N) {
        uint2 hs = h1s[node];
        float2 s01 = __half22float2(*(__half2*)&hs.x);
        float2 s23 = __half22float2(*(__half2*)&hs.y);
        unsigned long long rA = accA[threadIdx.x];
        unsigned long long rB = accB[threadIdx.x];
        float dv = dis[node];
        float v0 = dv * ((float)(unsigned)(rA)        * FINV + s01.x);
        float v1 = dv * ((float)(unsigned)(rA >> 32)  * FINV + s01.y);
        float v2 = dv * ((float)(unsigned)(rB)        * FINV + s23.x);
        float v3 = dv * ((float)(unsigned)(rB >> 32)  * FINV + s23.y);
        float a0 = fmaxf(v0 * W2[0] + v1 * W2[4] + v2 * W2[8]  + v3 * W2[12] + b2[0], 0.f);
        float a1 = fmaxf(v0 * W2[1] + v1 * W2[5] + v2 * W2[9]  + v3 * W2[13] + b2[1], 0.f);
        float a2 = fmaxf(v0 * W2[2] + v1 * W2[6] + v2 * W2[10] + v3 * W2[14] + b2[2], 0.f);
        float a3 = fmaxf(v0 * W2[3] + v1 * W2[7] + v2 * W2[11] + v3 * W2[15] + b2[3], 0.f);
        pt[node] = (a0 * W3[0] + a1 * W3[1] + a2 * W3[2] + a3 * W3[3]) * dv;
    }
}

// layer3 + fused global_add_pool
__global__ void k_g3f(const int* __restrict__ start, const int* __restrict__ binned,
                      const float* __restrict__ pt, const float* __restrict__ dis,
                      const int* __restrict__ batch, const float* __restrict__ b3,
                      float* __restrict__ out, int N, int E, int nbuck) {
    __shared__ float acc[NPB];
    __shared__ float g[NGRAPH];
    int b = blockIdx.x;
    acc[threadIdx.x] = 0.f;
    if (threadIdx.x < NGRAPH) g[threadIdx.x] = 0.f;
    __syncthreads();
    int a = start[(size_t)b * GWG];
    int e = (b + 1 < nbuck) ? start[(size_t)(b + 1) * GWG] : E;
    for (int j = a + threadIdx.x; j < e; j += NPB)
    {
        unsigned rec = (unsigned)binned[j];
        atomicAdd(&acc[rec >> SHIFT], pt[rec & SMASK]);
    }
    __syncthreads();
    int node = (b << LB) + threadIdx.x;
    if (node < N) {
        float y = dis[node] * (acc[threadIdx.x] + pt[node]) + b3[0];
        atomicAdd(&g[batch[node]], y);
    }
    __syncthreads();
    if (threadIdx.x < NGRAPH) {
        float v = g[threadIdx.x];
        if (v != 0.f) atomicAdd(out + threadIdx.x, v);
    }
}

// ===================== fallback: validated R2 CSR path =====================

__global__ void k_hist(const int* __restrict__ dst, int* __restrict__ deg, int E) {
    int tid = blockIdx.x * blockDim.x + threadIdx.x;
    int st  = gridDim.x * blockDim.x;
    int E4  = E >> 2;
    const int4* d4 = (const int4*)dst;
    for (int i = tid; i < E4; i += st) {
        int4 d = d4[i];
        atomicAdd(deg + d.x, 1);
        atomicAdd(deg + d.y, 1);
        atomicAdd(deg + d.z, 1);
        atomicAdd(deg + d.w, 1);
    }
    for (int i = (E4 << 2) + tid; i < E; i += st) atomicAdd(deg + dst[i], 1);
}

__global__ void k_scan1(const int* __restrict__ deg, int* __restrict__ bsum, int N) {
    __shared__ int sh[SCAN_T];
    int base = blockIdx.x * SCAN_B + threadIdx.x * SCAN_V;
    int s = 0;
#pragma unroll
    for (int k = 0; k < SCAN_V; ++k) {
        int idx = base + k;
        if (idx < N) s += deg[idx];
    }
    sh[threadIdx.x] = s;
    __syncthreads();
    for (int o = SCAN_T / 2; o > 0; o >>= 1) {
        if (threadIdx.x < o) sh[threadIdx.x] += sh[threadIdx.x + o];
        __syncthreads();
    }
    if (threadIdx.x == 0) bsum[blockIdx.x] = sh[0];
}

__global__ void k_scan2(int* __restrict__ bsum, int nb) {
    __shared__ int sh[1024];
    int t = threadIdx.x;
    int v = (t < nb) ? bsum[t] : 0;
    sh[t] = v;
    __syncthreads();
    for (int o = 1; o < 1024; o <<= 1) {
        int u = (t >= o) ? sh[t - o] : 0;
        __syncthreads();
        sh[t] += u;
        __syncthreads();
    }
    if (t < nb) bsum[t] = sh[t] - v;
}

__global__ void k_scan3(const int* __restrict__ deg, const int* __restrict__ bsum,
                        const float* __restrict__ x,
                        int* __restrict__ off, int* __restrict__ cur,
                        float* __restrict__ dis, float* __restrict__ px,
                        int N, int E) {
    __shared__ int sh[SCAN_T];
    int t = threadIdx.x;
    int base = blockIdx.x * SCAN_B + t * SCAN_V;
    int d[SCAN_V];
    int s = 0;
#pragma unroll
    for (int k = 0; k < SCAN_V; ++k) {
        int idx = base + k;
        d[k] = (idx < N) ? deg[idx] : 0;
        s += d[k];
    }
    sh[t] = s;
    __syncthreads();
    for (int o = 1; o < SCAN_T; o <<= 1) {
        int u = (t >= o) ? sh[t - o] : 0;
        __syncthreads();
        sh[t] += u;
        __syncthreads();
    }
    int run = bsum[blockIdx.x] + sh[t] - s;
#pragma unroll
    for (int k = 0; k < SCAN_V; ++k) {
        int idx = base + k;
        if (idx < N) {
            off[idx] = run;
            cur[idx] = run;
            float dv = rsqrtf((float)d[k] + 1.0f);
            dis[idx] = dv;
            px[idx]  = x[idx] * dv;
            run += d[k];
        }
    }
    if (blockIdx.x == 0 && t == 0) off[N] = E;
}

__global__ void k_build(const int* __restrict__ src, const int* __restrict__ dst,
                        int* __restrict__ cur, int* __restrict__ csr, int E) {
    int tid = blockIdx.x * blockDim.x + threadIdx.x;
    int st  = gridDim.x * blockDim.x;
    int E4  = E >> 2;
    const int4* s4 = (const int4*)src;
    const int4* d4 = (const int4*)dst;
    for (int i = tid; i < E4; i += st) {
        int4 s = s4[i];
        int4 d = d4[i];
        csr[atomicAdd(cur + d.x, 1)] = s.x;
        csr[atomicAdd(cur + d.y, 1)] = s.y;
        csr[atomicAdd(cur + d.z, 1)] = s.z;
        csr[atomicAdd(cur + d.w, 1)] = s.w;
    }
    for (int i = (E4 << 2) + tid; i < E; i += st)
        csr[atomicAdd(cur + dst[i], 1)] = src[i];
}

__global__ void k_gnode1(const int* __restrict__ off, const int* __restrict__ csr,
                         const float* __restrict__ px, const float* __restrict__ dis,
                         const float* __restrict__ W1, const float* __restrict__ b1,
                         float4* __restrict__ h1s, int N) {
    float w0 = W1[0], w1 = W1[1], w2 = W1[2], w3 = W1[3];
    float c0 = b1[0], c1 = b1[1], c2 = b1[2], c3 = b1[3];
    int i = blockIdx.x * blockDim.x + threadIdx.x;
    if (i >= N) return;
    int a = off[i], b = off[i + 1];
    float s = 0.f;
    for (int j = a; j < b; ++j) s += px[csr[j]];
    float dv = dis[i];
    float av = dv * (s + px[i]);
    float4 h;
    h.x = fmaxf(fmaf(av, w0, c0), 0.f) * dv;
    h.y = fmaxf(fmaf(av, w1, c1), 0.f) * dv;
    h.z = fmaxf(fmaf(av, w2, c2), 0.f) * dv;
    h.w = fmaxf(fmaf(av, w3, c3), 0.f) * dv;
    h1s[i] = h;
}

__global__ void k_gnode2(const int* __restrict__ off, const int* __restrict__ csr,
                         const float4* __restrict__ h1s, const float* __restrict__ dis,
                         const float* __restrict__ W2, const float* __restrict__ b2,
                         const float* __restrict__ W3, float* __restrict__ pt, int N) {
    float w[16];
#pragma unroll
    for (int k = 0; k < 16; ++k) w[k] = W2[k];
    float c0 = b2[0], c1 = b2[1], c2 = b2[2], c3 = b2[3];
    float u0 = W3[0], u1 = W3[1], u2 = W3[2], u3 = W3[3];
    int i = blockIdx.x * blockDim.x + threadIdx.x;
    if (i >= N) return;
    int a = off[i], b = off[i + 1];
    float s0 = 0.f, s1 = 0.f, s2 = 0.f, s3 = 0.f;
    for (int j = a; j < b; ++j) {
        float4 h = h1s[csr[j]];
        s0 += h.x; s1 += h.y; s2 += h.z; s3 += h.w;
    }
    float4 hs = h1s[i];
    float dv = dis[i];
    float v0 = dv * (s0 + hs.x);
    float v1 = dv * (s1 + hs.y);
    float v2 = dv * (s2 + hs.z);
    float v3 = dv * (s3 + hs.w);
    float a0 = fmaxf(v0 * w[0] + v1 * w[4] + v2 * w[8]  + v3 * w[12] + c0, 0.f);
    float a1 = fmaxf(v0 * w[1] + v1 * w[5] + v2 * w[9]  + v3 * w[13] + c1, 0.f);
    float a2 = fmaxf(v0 * w[2] + v1 * w[6] + v2 * w[10] + v3 * w[14] + c2, 0.f);
    float a3 = fmaxf(v0 * w[3] + v1 * w[7] + v2 * w[11] + v3 * w[15] + c3, 0.f);
    pt[i] = (a0 * u0 + a1 * u1 + a2 * u2 + a3 * u3) * dv;
}

__global__ void k_gpool(const int* __restrict__ off, const int* __restrict__ csr,
                        const float* __restrict__ pt, const float* __restrict__ dis,
                        const int* __restrict__ batch, const float* __restrict__ b3,
                        float* __restrict__ out, int N) {
    __shared__ float g[NGRAPH];
    for (int j = threadIdx.x; j < NGRAPH; j += blockDim.x) g[j] = 0.f;
    __syncthreads();
    int i = blockIdx.x * blockDim.x + threadIdx.x;
    if (i < N) {
        int a = off[i], b = off[i + 1];
        float s = 0.f;
        for (int j = a; j < b; ++j) s += pt[csr[j]];
        float v = dis[i] * (s + pt[i]) + b3[0];
        atomicAdd(&g[batch[i]], v);
    }
    __syncthreads();
    for (int j = threadIdx.x; j < NGRAPH; j += blockDim.x) {
        float v = g[j];
        if (v != 0.f) atomicAdd(out + j, v);
    }
}

// ===================== launch =====================

extern "C" void kernel_launch(void* const* d_in, const int* in_sizes, int n_in,
                              void* d_out, int out_size, void* d_ws, size_t ws_size,
                              hipStream_t stream) {
    const float* x     = (const float*)d_in[0];
    const int*   ei    = (const int*)d_in[1];
    const int*   batch = (const int*)d_in[2];
    const float* W1 = (const float*)d_in[3];
    const float* b1 = (const float*)d_in[4];
    const float* W2 = (const float*)d_in[5];
    const float* b2 = (const float*)d_in[6];
    const float* W3 = (const float*)d_in[7];
    const float* b3 = (const float*)d_in[8];

    int N = in_sizes[0];
    int E = in_sizes[1] / 2;
    const int* src = ei;
    const int* dst = ei + E;

    const int blk = 256;
    int nbuck = (N + NPB - 1) >> LB;
    size_t M  = (size_t)nbuck * GWG;                 // cnt/start matrix elems
    int chunk = (int)(((E + GWG - 1) / GWG + 3) & ~3);
    int nblk  = (int)((M + SCAN_B - 1) / SCAN_B);

    size_t Np = ((size_t)N + 4 + 3) & ~(size_t)3;    // >= N+1, multiple of 4
    size_t part_need = (2 * M + 2048 + 6 * Np + (size_t)E) * sizeof(int);

    hipMemsetAsync(d_out, 0, (size_t)out_size * sizeof(float), stream);

    if (N < (1 << SHIFT) && nbuck <= MAXB && nblk <= 1024 && ws_size >= part_need) {
        // ---- two-pass partition path ----
        int*   cnt    = (int*)d_ws;                  // [M]
        int*   startm = cnt + M;                     // [M]
        int*   bs     = startm + M;                  // [2048]
        float* dis    = (float*)(bs + 2048);         // [Np]
        float* pxpt   = dis + Np;                    // [Np]  px for L1, then pt for L3
        uint2* h1s    = (uint2*)(pxpt + Np);         // [Np]  fp16x4 per node (8B)
        int*   binned = (int*)(h1s + Np);            // [E]

        k_p1 <<<GWG, blk, 0, stream>>>(dst, cnt, E, chunk, nbuck);
        k_sA <<<nblk, SCAN_T, 0, stream>>>(cnt, bs, (int)M);
        k_sB <<<1, 1024, 0, stream>>>(bs, nblk);
        k_sC <<<nblk, SCAN_T, 0, stream>>>(cnt, bs, startm, (int)M);
        k_p2 <<<GWG, TPB, 0, stream>>>(src, dst, startm, binned, E, chunk, nbuck);
        k_boff<<<nbuck, NPB, 0, stream>>>(startm, binned, x, dis, pxpt, N, E, nbuck);
        k_g1 <<<nbuck, NPB, 0, stream>>>(startm, binned, pxpt, dis, W1, b1,
                                         h1s, N, E, nbuck);
        k_g4 <<<nbuck, NPB, 0, stream>>>(startm, binned, (const uint2*)h1s, dis,
                                         W2, b2, W3, pxpt, N, E, nbuck);
        k_g3f<<<nbuck, NPB, 0, stream>>>(startm, binned, pxpt, dis, batch, b3,
                                         (float*)d_out, N, E, nbuck);
    } else {
        // ---- fallback: R2 CSR gather path ----
        int*   deg  = (int*)d_ws;
        int*   off  = deg + Np;
        int*   cur  = off + Np;
        float* dis  = (float*)(cur + Np);
        float* px   = dis + Np;
        float* pt   = px + Np;
        int*   bsum = (int*)(pt + Np);
        float* h1s  = (float*)(bsum + Np);
        int*   csr  = (int*)(h1s + 4 * Np);

        hipMemsetAsync(deg, 0, Np * sizeof(int), stream);

        int nb    = (N + SCAN_B - 1) / SCAN_B;
        int ngrid = (N + blk - 1) / blk;
        int egrid = 8192;

        k_hist <<<egrid, blk, 0, stream>>>(dst, deg, E);
        k_scan1<<<nb, SCAN_T, 0, stream>>>(deg, bsum, N);
        k_scan2<<<1, 1024, 0, stream>>>(bsum, nb);
        k_scan3<<<nb, SCAN_T, 0, stream>>>(deg, bsum, x, off, cur, dis, px, N, E);
        k_build<<<egrid, blk, 0, stream>>>(src, dst, cur, csr, E);
        k_gnode1<<<ngrid, blk, 0, stream>>>(off, csr, px, dis, W1, b1, (float4*)h1s, N);
        k_gnode2<<<ngrid, blk, 0, stream>>>(off, csr, (const float4*)h1s, dis, W2, b2, W3, pt, N);
        k_gpool <<<ngrid, blk, 0, stream>>>(off, csr, pt, dis, batch, b3, (float*)d_out, N);
    }
}

// Round 22
// 371.814 us; speedup vs baseline: 1.4671x; 1.0460x over previous
//
#include <hip/hip_runtime.h>
#include <hip/hip_fp16.h>

#define NGRAPH 512
#define SCAN_T 256
#define SCAN_V 4
#define SCAN_B (SCAN_T * SCAN_V)

// bucket scheme: 1024 nodes per bucket, two-pass WG-private radix partition.
#define LB 10
#define NPB 1024
#define SHIFT 22
#define SMASK ((1 << SHIFT) - 1)
#define MAXB 512
#define GWG 1024  // partition workgroups: 4 WGs/CU (R20 showed 512 = grid-capped 25% occupancy)

#define TILE 4096
#define TPB 256
#define EPT (TILE / TPB)   // 16 edges per thread per tile

#define FSCALE 16777216.0f          // 2^24 fixed-point scale
#define FINV   (1.0f / 16777216.0f)

// ===================== two-pass partition =====================

// pass1: per-WG LDS bucket histogram over private chunk -> cnt[bucket][GWG]
__global__ void k_p1(const int* __restrict__ dst, int* __restrict__ cnt,
                     int E, int chunk, int nbuck) {
    __shared__ int hist[MAXB];
    int w = blockIdx.x;
    for (int i = threadIdx.x; i < nbuck; i += blockDim.x) hist[i] = 0;
    __syncthreads();
    int beg = w * chunk;
    int end = min(beg + chunk, E);
    if (beg < end) {
        if ((((uintptr_t)(dst + beg)) & 15) == 0) {
            const int4* d4 = (const int4*)(dst + beg);
            int n4 = (end - beg) >> 2;
            for (int i = threadIdx.x; i < n4; i += blockDim.x) {
                int4 d = d4[i];
                atomicAdd(&hist[d.x >> LB], 1);
                atomicAdd(&hist[d.y >> LB], 1);
                atomicAdd(&hist[d.z >> LB], 1);
                atomicAdd(&hist[d.w >> LB], 1);
            }
            for (int i = beg + (n4 << 2) + threadIdx.x; i < end; i += blockDim.x)
                atomicAdd(&hist[dst[i] >> LB], 1);
        } else {
            for (int i = beg + threadIdx.x; i < end; i += blockDim.x)
                atomicAdd(&hist[dst[i] >> LB], 1);
        }
    }
    __syncthreads();
    for (int b = threadIdx.x; b < nbuck; b += blockDim.x)
        cnt[(size_t)b * GWG + w] = hist[b];
}

// scanA: per-block (1024-elem) sums of cnt -> bs
__global__ void k_sA(const int* __restrict__ cnt, int* __restrict__ bs, int M) {
    __shared__ int sh[SCAN_T];
    int base = blockIdx.x * SCAN_B + threadIdx.x * SCAN_V;
    int s = 0;
#pragma unroll
    for (int k = 0; k < SCAN_V; ++k) {
        int idx = base + k;
        if (idx < M) s += cnt[idx];
    }
    sh[threadIdx.x] = s;
    __syncthreads();
    for (int o = SCAN_T / 2; o > 0; o >>= 1) {
        if (threadIdx.x < o) sh[threadIdx.x] += sh[threadIdx.x + o];
        __syncthreads();
    }
    if (threadIdx.x == 0) bs[blockIdx.x] = sh[0];
}

// scanB: single block, 1024 threads: exclusive scan of bs[0..nb)
__global__ void k_sB(int* __restrict__ bs, int nb) {
    __shared__ int sh[1024];
    int t = threadIdx.x;
    int v = (t < nb) ? bs[t] : 0;
    sh[t] = v;
    __syncthreads();
    for (int o = 1; o < 1024; o <<= 1) {
        int u = (t >= o) ? sh[t - o] : 0;
        __syncthreads();
        sh[t] += u;
        __syncthreads();
    }
    if (t < nb) bs[t] = sh[t] - v;
}

// scanC: full exclusive scan -> start[bucket][GWG]
__global__ void k_sC(const int* __restrict__ cnt, const int* __restrict__ bs,
                     int* __restrict__ start, int M) {
    __shared__ int sh[SCAN_T];
    int t = threadIdx.x;
    int base = blockIdx.x * SCAN_B + t * SCAN_V;
    int v[SCAN_V];
    int s = 0;
#pragma unroll
    for (int k = 0; k < SCAN_V; ++k) {
        int idx = base + k;
        v[k] = (idx < M) ? cnt[idx] : 0;
        s += v[k];
    }
    sh[t] = s;
    __syncthreads();
    for (int o = 1; o < SCAN_T; o <<= 1) {
        int u = (t >= o) ? sh[t - o] : 0;
        __syncthreads();
        sh[t] += u;
        __syncthreads();
    }
    int run = bs[blockIdx.x] + sh[t] - s;
#pragma unroll
    for (int k = 0; k < SCAN_V; ++k) {
        int idx = base + k;
        if (idx < M) {
            start[idx] = run;
            run += v[k];
        }
    }
}

// pass2: per-tile LDS counting sort with shfl wave-scan; bucket-grouped
// contiguous writes keep L2 write coalescing (validated R19/R20).
__global__ void k_p2(const int* __restrict__ src, const int* __restrict__ dst,
                     const int* __restrict__ start, int* __restrict__ binned,
                     int E, int chunk, int nbuck) {
    __shared__ int   cur[MAXB];
    __shared__ int   hist[MAXB];
    __shared__ int   pl[MAXB];
    __shared__ int   wsum[4];
    __shared__ int   buf[TILE];
    __shared__ short bkt[TILE];
    int tid  = threadIdx.x;
    int lane = tid & 63;
    int wave = tid >> 6;
    int w = blockIdx.x;
    for (int b = tid; b < nbuck; b += TPB) cur[b] = start[(size_t)b * GWG + w];
    __syncthreads();
    int beg = w * chunk;
    int end = min(beg + chunk, E);
    for (int t0 = beg; t0 < end; t0 += TILE) {
        int tcnt = min(TILE, end - t0);
        for (int b = tid; b < MAXB; b += TPB) hist[b] = 0;
        __syncthreads();
        // phase 1: load (coalesced) + tile histogram
        int   r[EPT];
        short bb[EPT];
#pragma unroll
        for (int k = 0; k < EPT; ++k) {
            int i = t0 + k * TPB + tid;
            if (i < end) {
                int s = src[i], d = dst[i];
                bb[k] = (short)(d >> LB);
                r[k]  = ((d & (NPB - 1)) << SHIFT) | s;
                atomicAdd(&hist[(int)bb[k]], 1);
            } else {
                bb[k] = -1;
            }
        }
        __syncthreads();
        // exclusive scan of hist[0..MAXB) via per-wave shfl scan, 2 elems/thread
        int e0 = tid * 2, e1 = tid * 2 + 1;
        int v0 = hist[e0], v1 = hist[e1];
        int s = v0 + v1;
        for (int o = 1; o < 64; o <<= 1) {
            int u = __shfl_up(s, o);
            if (lane >= o) s += u;
        }
        if (lane == 63) wsum[wave] = s;
        __syncthreads();
        int ew = 0;
        for (int k = 0; k < wave; ++k) ew += wsum[k];
        int incl1 = ew + s;            // inclusive prefix through e1
        pl[e1] = incl1 - v1;           // exclusive for e1
        pl[e0] = incl1 - v1 - v0;      // exclusive for e0
        __syncthreads();
        // phase 2: place into LDS grouped by bucket
#pragma unroll
        for (int k = 0; k < EPT; ++k) {
            if (bb[k] >= 0) {
                int pos = atomicAdd(&pl[(int)bb[k]], 1);
                buf[pos] = r[k];
                bkt[pos] = bb[k];
            }
        }
        __syncthreads();
        // phase 3: bucket-grouped contiguous global writes
        // (pl now = exclusive + hist, so exclusive offset = pl[b] - hist[b])
        for (int p = tid; p < tcnt; p += TPB) {
            int b = (int)bkt[p];
            int off = pl[b] - hist[b];
            binned[cur[b] + (p - off)] = buf[p];
        }
        __syncthreads();
        for (int b = tid; b < nbuck; b += TPB) cur[b] += hist[b];
        __syncthreads();
    }
}

// ===================== per-bucket layers (LDS accumulators, 1024-thr blocks) ===

// degree hist -> dis, px
__global__ void k_boff(const int* __restrict__ start, const int* __restrict__ binned,
                       const float* __restrict__ x, float* __restrict__ dis,
                       float* __restrict__ px, int N, int E, int nbuck) {
    __shared__ int hist[NPB];
    int b = blockIdx.x;
    hist[threadIdx.x] = 0;
    __syncthreads();
    int a = start[(size_t)b * GWG];
    int e = (b + 1 < nbuck) ? start[(size_t)(b + 1) * GWG] : E;
    for (int j = a + threadIdx.x; j < e; j += NPB)
        atomicAdd(&hist[((unsigned)binned[j]) >> SHIFT], 1);
    __syncthreads();
    int node = (b << LB) + threadIdx.x;
    if (node < N) {
        float dv = rsqrtf((float)hist[threadIdx.x] + 1.0f);
        dis[node] = dv;
        px[node]  = x[node] * dv;
    }
}

// layer1: h1s(fp16x4) = relu(dis*(acc+px)*W1+b1)*dis
__global__ void k_g1(const int* __restrict__ start, const int* __restrict__ binned,
                     const float* __restrict__ px, const float* __restrict__ dis,
                     const float* __restrict__ W1, const float* __restrict__ b1,
                     uint2* __restrict__ h1s, int N, int E, int nbuck) {
    __shared__ float acc[NPB];
    int b = blockIdx.x;
    acc[threadIdx.x] = 0.f;
    __syncthreads();
    int a = start[(size_t)b * GWG];
    int e = (b + 1 < nbuck) ? start[(size_t)(b + 1) * GWG] : E;
    for (int j = a + threadIdx.x; j < e; j += NPB) {
        unsigned rec = (unsigned)binned[j];
        atomicAdd(&acc[rec >> SHIFT], px[rec & SMASK]);
    }
    __syncthreads();
    int node = (b << LB) + threadIdx.x;
    if (node < N) {
        float dv = dis[node];
        float av = dv * (acc[threadIdx.x] + px[node]);
        float hx = fmaxf(fmaf(av, W1[0], b1[0]), 0.f) * dv;
        float hy = fmaxf(fmaf(av, W1[1], b1[1]), 0.f) * dv;
        float hz = fmaxf(fmaf(av, W1[2], b1[2]), 0.f) * dv;
        float hw = fmaxf(fmaf(av, W1[3], b1[3]), 0.f) * dv;
        __half2 lo = __floats2half2_rn(hx, hy);
        __half2 hi = __floats2half2_rn(hz, hw);
        uint2 r;
        r.x = *(unsigned int*)&lo;
        r.y = *(unsigned int*)&hi;
        h1s[node] = r;
    }
}

__device__ __forceinline__ void unpack_h4(uint2 r, float& f0, float& f1,
                                          float& f2, float& f3) {
    __half2 lo = *(__half2*)&r.x;
    __half2 hi = *(__half2*)&r.y;
    float2 a = __half22float2(lo);
    float2 b = __half22float2(hi);
    f0 = a.x; f1 = a.y; f2 = b.x; f3 = b.y;
}

// layer2: pt = (relu(dis*(acc+self)@W2+b2)@W3)*dis
// fixed-point packed u64 LDS atomics: 2 ds_add_u64 per edge (validated R16).
__global__ void k_g4(const int* __restrict__ start, const int* __restrict__ binned,
                     const uint2* __restrict__ h1s, const float* __restrict__ dis,
                     const float* __restrict__ W2, const float* __restrict__ b2,
                     const float* __restrict__ W3, float* __restrict__ pt,
                     int N, int E, int nbuck) {
    __shared__ unsigned long long accA[NPB];  // feat0 (lo32) | feat1 (hi32)
    __shared__ unsigned long long accB[NPB];  // feat2 (lo32) | feat3 (hi32)
    int b = blockIdx.x;
    accA[threadIdx.x] = 0ull;
    accB[threadIdx.x] = 0ull;
    __syncthreads();
    int a = start[(size_t)b * GWG];
    int e = (b + 1 < nbuck) ? start[(size_t)(b + 1) * GWG] : E;
    int j = a + threadIdx.x;
    for (; j + NPB < e; j += 2 * NPB) {
        unsigned r0 = (unsigned)binned[j];
        unsigned r1 = (unsigned)binned[j + NPB];
        uint2 q0 = h1s[r0 & SMASK];
        uint2 q1 = h1s[r1 & SMASK];
        float2 a01 = __half22float2(*(__half2*)&q0.x);
        float2 a23 = __half22float2(*(__half2*)&q0.y);
        float2 c01 = __half22float2(*(__half2*)&q1.x);
        float2 c23 = __half22float2(*(__half2*)&q1.y);
        int l0 = (int)(r0 >> SHIFT);
        int l1 = (int)(r1 >> SHIFT);
        unsigned long long pA0 = (unsigned long long)(unsigned)(a01.x * FSCALE)
                               | ((unsigned long long)(unsigned)(a01.y * FSCALE) << 32);
        unsigned long long pB0 = (unsigned long long)(unsigned)(a23.x * FSCALE)
                               | ((unsigned long long)(unsigned)(a23.y * FSCALE) << 32);
        unsigned long long pA1 = (unsigned long long)(unsigned)(c01.x * FSCALE)
                               | ((unsigned long long)(unsigned)(c01.y * FSCALE) << 32);
        unsigned long long pB1 = (unsigned long long)(unsigned)(c23.x * FSCALE)
                               | ((unsigned long long)(unsigned)(c23.y * FSCALE) << 32);
        atomicAdd(&accA[l0], pA0);
        atomicAdd(&accB[l0], pB0);
        atomicAdd(&accA[l1], pA1);
        atomicAdd(&accB[l1], pB1);
    }
    if (j < e) {
        unsigned r0 = (unsigned)binned[j];
        uint2 q0 = h1s[r0 & SMASK];
        float2 a01 = __half22float2(*(__half2*)&q0.x);
        float2 a23 = __half22float2(*(__half2*)&q0.y);
        int l0 = (int)(r0 >> SHIFT);
        unsigned long long pA0 = (unsigned long long)(unsigned)(a01.x * FSCALE)
                               | ((unsigned long long)(unsigned)(a01.y * FSCALE) << 32);
        unsigned long long pB0 = (unsigned long long)(unsigned)(a23.x * FSCALE)
                               | ((unsigned long long)(unsigned)(a23.y * FSCALE) << 32);
        atomicAdd(&accA[l0], pA0);
        atomicAdd(&accB[l0], pB0);
    }
    __syncthreads();
    int node = (b << LB) + threadIdx.x;
    if (node < N) {
        uint2 hs = h1s[node];
        float2 s01 = __half22float2(*(__half2*)&hs.x);
        float2 s23 = __half22float2(*(__half2*)&hs.y);
        unsigned long long rA = accA[threadIdx.x];
        unsigned long long rB = accB[threadIdx.x];
        float dv = dis[node];
        float v0 = dv * ((float)(unsigned)(rA)        * FINV + s01.x);
        float v1 = dv * ((float)(unsigned)(rA >> 32)  * FINV + s01.y);
        float v2 = dv * ((float)(unsigned)(rB)        * FINV + s23.x);
        float v3 = dv * ((float)(unsigned)(rB >> 32)  * FINV + s23.y);
        float a0 = fmaxf(v0 * W2[0] + v1 * W2[4] + v2 * W2[8]  + v3 * W2[12] + b2[0], 0.f);
        float a1 = fmaxf(v0 * W2[1] + v1 * W2[5] + v2 * W2[9]  + v3 * W2[13] + b2[1], 0.f);
        float a2 = fmaxf(v0 * W2[2] + v1 * W2[6] + v2 * W2[10] + v3 * W2[14] + b2[2], 0.f);
        float a3 = fmaxf(v0 * W2[3] + v1 * W2[7] + v2 * W2[11] + v3 * W2[15] + b2[3], 0.f);
        pt[node] = (a0 * W3[0] + a1 * W3[1] + a2 * W3[2] + a3 * W3[3]) * dv;
    }
}

// layer3 + fused global_add_pool
__global__ void k_g3f(const int* __restrict__ start, const int* __restrict__ binned,
                      const float* __restrict__ pt, const float* __restrict__ dis,
                      const int* __restrict__ batch, const float* __restrict__ b3,
                      float* __restrict__ out, int N, int E, int nbuck) {
    __shared__ float acc[NPB];
    __shared__ float g[NGRAPH];
    int b = blockIdx.x;
    acc[threadIdx.x] = 0.f;
    if (threadIdx.x < NGRAPH) g[threadIdx.x] = 0.f;
    __syncthreads();
    int a = start[(size_t)b * GWG];
    int e = (b + 1 < nbuck) ? start[(size_t)(b + 1) * GWG] : E;
    for (int j = a + threadIdx.x; j < e; j += NPB)
    {
        unsigned rec = (unsigned)binned[j];
        atomicAdd(&acc[rec >> SHIFT], pt[rec & SMASK]);
    }
    __syncthreads();
    int node = (b << LB) + threadIdx.x;
    if (node < N) {
        float y = dis[node] * (acc[threadIdx.x] + pt[node]) + b3[0];
        atomicAdd(&g[batch[node]], y);
    }
    __syncthreads();
    if (threadIdx.x < NGRAPH) {
        float v = g[threadIdx.x];
        if (v != 0.f) atomicAdd(out + threadIdx.x, v);
    }
}

// ===================== fallback: validated R2 CSR path =====================

__global__ void k_hist(const int* __restrict__ dst, int* __restrict__ deg, int E) {
    int tid = blockIdx.x * blockDim.x + threadIdx.x;
    int st  = gridDim.x * blockDim.x;
    int E4  = E >> 2;
    const int4* d4 = (const int4*)dst;
    for (int i = tid; i < E4; i += st) {
        int4 d = d4[i];
        atomicAdd(deg + d.x, 1);
        atomicAdd(deg + d.y, 1);
        atomicAdd(deg + d.z, 1);
        atomicAdd(deg + d.w, 1);
    }
    for (int i = (E4 << 2) + tid; i < E; i += st) atomicAdd(deg + dst[i], 1);
}

__global__ void k_scan1(const int* __restrict__ deg, int* __restrict__ bsum, int N) {
    __shared__ int sh[SCAN_T];
    int base = blockIdx.x * SCAN_B + threadIdx.x * SCAN_V;
    int s = 0;
#pragma unroll
    for (int k = 0; k < SCAN_V; ++k) {
        int idx = base + k;
        if (idx < N) s += deg[idx];
    }
    sh[threadIdx.x] = s;
    __syncthreads();
    for (int o = SCAN_T / 2; o > 0; o >>= 1) {
        if (threadIdx.x < o) sh[threadIdx.x] += sh[threadIdx.x + o];
        __syncthreads();
    }
    if (threadIdx.x == 0) bsum[blockIdx.x] = sh[0];
}

__global__ void k_scan2(int* __restrict__ bsum, int nb) {
    __shared__ int sh[1024];
    int t = threadIdx.x;
    int v = (t < nb) ? bsum[t] : 0;
    sh[t] = v;
    __syncthreads();
    for (int o = 1; o < 1024; o <<= 1) {
        int u = (t >= o) ? sh[t - o] : 0;
        __syncthreads();
        sh[t] += u;
        __syncthreads();
    }
    if (t < nb) bsum[t] = sh[t] - v;
}

__global__ void k_scan3(const int* __restrict__ deg, const int* __restrict__ bsum,
                        const float* __restrict__ x,
                        int* __restrict__ off, int* __restrict__ cur,
                        float* __restrict__ dis, float* __restrict__ px,
                        int N, int E) {
    __shared__ int sh[SCAN_T];
    int t = threadIdx.x;
    int base = blockIdx.x * SCAN_B + t * SCAN_V;
    int d[SCAN_V];
    int s = 0;
#pragma unroll
    for (int k = 0; k < SCAN_V; ++k) {
        int idx = base + k;
        d[k] = (idx < N) ? deg[idx] : 0;
        s += d[k];
    }
    sh[t] = s;
    __syncthreads();
    for (int o = 1; o < SCAN_T; o <<= 1) {
        int u = (t >= o) ? sh[t - o] : 0;
        __syncthreads();
        sh[t] += u;
        __syncthreads();
    }
    int run = bsum[blockIdx.x] + sh[t] - s;
#pragma unroll
    for (int k = 0; k < SCAN_V; ++k) {
        int idx = base + k;
        if (idx < N) {
            off[idx] = run;
            cur[idx] = run;
            float dv = rsqrtf((float)d[k] + 1.0f);
            dis[idx] = dv;
            px[idx]  = x[idx] * dv;
            run += d[k];
        }
    }
    if (blockIdx.x == 0 && t == 0) off[N] = E;
}

__global__ void k_build(const int* __restrict__ src, const int* __restrict__ dst,
                        int* __restrict__ cur, int* __restrict__ csr, int E) {
    int tid = blockIdx.x * blockDim.x + threadIdx.x;
    int st  = gridDim.x * blockDim.x;
    int E4  = E >> 2;
    const int4* s4 = (const int4*)src;
    const int4* d4 = (const int4*)dst;
    for (int i = tid; i < E4; i += st) {
        int4 s = s4[i];
        int4 d = d4[i];
        csr[atomicAdd(cur + d.x, 1)] = s.x;
        csr[atomicAdd(cur + d.y, 1)] = s.y;
        csr[atomicAdd(cur + d.z, 1)] = s.z;
        csr[atomicAdd(cur + d.w, 1)] = s.w;
    }
    for (int i = (E4 << 2) + tid; i < E; i += st)
        csr[atomicAdd(cur + dst[i], 1)] = src[i];
}

__global__ void k_gnode1(const int* __restrict__ off, const int* __restrict__ csr,
                         const float* __restrict__ px, const float* __restrict__ dis,
                         const float* __restrict__ W1, const float* __restrict__ b1,
                         float4* __restrict__ h1s, int N) {
    float w0 = W1[0], w1 = W1[1], w2 = W1[2], w3 = W1[3];
    float c0 = b1[0], c1 = b1[1], c2 = b1[2], c3 = b1[3];
    int i = blockIdx.x * blockDim.x + threadIdx.x;
    if (i >= N) return;
    int a = off[i], b = off[i + 1];
    float s = 0.f;
    for (int j = a; j < b; ++j) s += px[csr[j]];
    float dv = dis[i];
    float av = dv * (s + px[i]);
    float4 h;
    h.x = fmaxf(fmaf(av, w0, c0), 0.f) * dv;
    h.y = fmaxf(fmaf(av, w1, c1), 0.f) * dv;
    h.z = fmaxf(fmaf(av, w2, c2), 0.f) * dv;
    h.w = fmaxf(fmaf(av, w3, c3), 0.f) * dv;
    h1s[i] = h;
}

__global__ void k_gnode2(const int* __restrict__ off, const int* __restrict__ csr,
                         const float4* __restrict__ h1s, const float* __restrict__ dis,
                         const float* __restrict__ W2, const float* __restrict__ b2,
                         const float* __restrict__ W3, float* __restrict__ pt, int N) {
    float w[16];
#pragma unroll
    for (int k = 0; k < 16; ++k) w[k] = W2[k];
    float c0 = b2[0], c1 = b2[1], c2 = b2[2], c3 = b2[3];
    float u0 = W3[0], u1 = W3[1], u2 = W3[2], u3 = W3[3];
    int i = blockIdx.x * blockDim.x + threadIdx.x;
    if (i >= N) return;
    int a = off[i], b = off[i + 1];
    float s0 = 0.f, s1 = 0.f, s2 = 0.f, s3 = 0.f;
    for (int j = a; j < b; ++j) {
        float4 h = h1s[csr[j]];
        s0 += h.x; s1 += h.y; s2 += h.z; s3 += h.w;
    }
    float4 hs = h1s[i];
    float dv = dis[i];
    float v0 = dv * (s0 + hs.x);
    float v1 = dv * (s1 + hs.y);
    float v2 = dv * (s2 + hs.z);
    float v3 = dv * (s3 + hs.w);
    float a0 = fmaxf(v0 * w[0] + v1 * w[4] + v2 * w[8]  + v3 * w[12] + c0, 0.f);
    float a1 = fmaxf(v0 * w[1] + v1 * w[5] + v2 * w[9]  + v3 * w[13] + c1, 0.f);
    float a2 = fmaxf(v0 * w[2] + v1 * w[6] + v2 * w[10] + v3 * w[14] + c2, 0.f);
    float a3 = fmaxf(v0 * w[3] + v1 * w[7] + v2 * w[11] + v3 * w[15] + c3, 0.f);
    pt[i] = (a0 * u0 + a1 * u1 + a2 * u2 + a3 * u3) * dv;
}

__global__ void k_gpool(const int* __restrict__ off, const int* __restrict__ csr,
                        const float* __restrict__ pt, const float* __restrict__ dis,
                        const int* __restrict__ batch, const float* __restrict__ b3,
                        float* __restrict__ out, int N) {
    __shared__ float g[NGRAPH];
    for (int j = threadIdx.x; j < NGRAPH; j += blockDim.x) g[j] = 0.f;
    __syncthreads();
    int i = blockIdx.x * blockDim.x + threadIdx.x;
    if (i < N) {
        int a = off[i], b = off[i + 1];
        float s = 0.f;
        for (int j = a; j < b; ++j) s += pt[csr[j]];
        float v = dis[i] * (s + pt[i]) + b3[0];
        atomicAdd(&g[batch[i]], v);
    }
    __syncthreads();
    for (int j = threadIdx.x; j < NGRAPH; j += blockDim.x) {
        float v = g[j];
        if (v != 0.f) atomicAdd(out + j, v);
    }
}

// ===================== launch =====================

extern "C" void kernel_launch(void* const* d_in, const int* in_sizes, int n_in,
                              void* d_out, int out_size, void* d_ws, size_t ws_size,
                              hipStream_t stream) {
    const float* x     = (const float*)d_in[0];
    const int*   ei    = (const int*)d_in[1];
    const int*   batch = (const int*)d_in[2];
    const float* W1 = (const float*)d_in[3];
    const float* b1 = (const float*)d_in[4];
    const float* W2 = (const float*)d_in[5];
    const float* b2 = (const float*)d_in[6];
    const float* W3 = (const float*)d_in[7];
    const float* b3 = (const float*)d_in[8];

    int N = in_sizes[0];
    int E = in_sizes[1] / 2;
    const int* src = ei;
    const int* dst = ei + E;

    const int blk = 256;
    int nbuck = (N + NPB - 1) >> LB;
    size_t M  = (size_t)nbuck * GWG;                 // cnt/start matrix elems
    int chunk = (int)(((E + GWG - 1) / GWG + 3) & ~3);
    int nblk  = (int)((M + SCAN_B - 1) / SCAN_B);

    size_t Np = ((size_t)N + 4 + 3) & ~(size_t)3;    // >= N+1, multiple of 4
    size_t part_need = (2 * M + 2048 + 6 * Np + (size_t)E) * sizeof(int);

    hipMemsetAsync(d_out, 0, (size_t)out_size * sizeof(float), stream);

    if (N < (1 << SHIFT) && nbuck <= MAXB && nblk <= 1024 && ws_size >= part_need) {
        // ---- two-pass partition path ----
        int*   cnt    = (int*)d_ws;                  // [M]
        int*   startm = cnt + M;                     // [M]
        int*   bs     = startm + M;                  // [2048]
        float* dis    = (float*)(bs + 2048);         // [Np]
        float* pxpt   = dis + Np;                    // [Np]  px for L1, then pt for L3
        uint2* h1s    = (uint2*)(pxpt + Np);         // [Np]  fp16x4 per node (8B)
        int*   binned = (int*)(h1s + Np);            // [E]

        k_p1 <<<GWG, blk, 0, stream>>>(dst, cnt, E, chunk, nbuck);
        k_sA <<<nblk, SCAN_T, 0, stream>>>(cnt, bs, (int)M);
        k_sB <<<1, 1024, 0, stream>>>(bs, nblk);
        k_sC <<<nblk, SCAN_T, 0, stream>>>(cnt, bs, startm, (int)M);
        k_p2 <<<GWG, TPB, 0, stream>>>(src, dst, startm, binned, E, chunk, nbuck);
        k_boff<<<nbuck, NPB, 0, stream>>>(startm, binned, x, dis, pxpt, N, E, nbuck);
        k_g1 <<<nbuck, NPB, 0, stream>>>(startm, binned, pxpt, dis, W1, b1,
                                         h1s, N, E, nbuck);
        k_g4 <<<nbuck, NPB, 0, stream>>>(startm, binned, (const uint2*)h1s, dis,
                                         W2, b2, W3, pxpt, N, E, nbuck);
        k_g3f<<<nbuck, NPB, 0, stream>>>(startm, binned, pxpt, dis, batch, b3,
                                         (float*)d_out, N, E, nbuck);
    } else {
        // ---- fallback: R2 CSR gather path ----
        int*   deg  = (int*)d_ws;
        int*   off  = deg + Np;
        int*   cur  = off + Np;
        float* dis  = (float*)(cur + Np);
        float* px   = dis + Np;
        float* pt   = px + Np;
        int*   bsum = (int*)(pt + Np);
        float* h1s  = (float*)(bsum + Np);
        int*   csr  = (int*)(h1s + 4 * Np);

        hipMemsetAsync(deg, 0, Np * sizeof(int), stream);

        int nb    = (N + SCAN_B - 1) / SCAN_B;
        int ngrid = (N + blk - 1) / blk;
        int egrid = 8192;

        k_hist <<<egrid, blk, 0, stream>>>(dst, deg, E);
        k_scan1<<<nb, SCAN_T, 0, stream>>>(deg, bsum, N);
        k_scan2<<<1, 1024, 0, stream>>>(bsum, nb);
        k_scan3<<<nb, SCAN_T, 0, stream>>>(deg, bsum, x, off, cur, dis, px, N, E);
        k_build<<<egrid, blk, 0, stream>>>(src, dst, cur, csr, E);
        k_gnode1<<<ngrid, blk, 0, stream>>>(off, csr, px, dis, W1, b1, (float4*)h1s, N);
        k_gnode2<<<ngrid, blk, 0, stream>>>(off, csr, (const float4*)h1s, dis, W2, b2, W3, pt, N);
        k_gpool <<<ngrid, blk, 0, stream>>>(off, csr, pt, dis, batch, b3, (float*)d_out, N);
    }
}